// Round 5
// baseline (1428.094 us; speedup 1.0000x reference)
//
#include <hip/hip_runtime.h>
#include <hip/hip_bf16.h>
#include <cfloat>

#define N_TOK 8192
#define C_DIM 256
#define H_DIM 1024
#define E_ALL 32
#define E_RT  31
#define TN    128                      // tokens per block (8 waves x 16)
#define HC2   32                       // H per step
#define NST   (H_DIM / HC2)            // 32 steps
#define STEP_B (HC2 * C_DIM * 2)       // 16384 bytes per weight chunk

typedef __attribute__((ext_vector_type(8))) short bf16x8;
typedef __attribute__((ext_vector_type(4))) float f32x4;

__device__ __forceinline__ unsigned short f2bf(float f) {
    return __builtin_bit_cast(unsigned short, __float2bfloat16(f));
}
__device__ __forceinline__ float bf2f(unsigned short u) {
    unsigned int x = ((unsigned int)u) << 16;
    return __builtin_bit_cast(float, x);
}
__device__ __forceinline__ void gld16(void* lds, const void* g) {
    __builtin_amdgcn_global_load_lds(
        (const __attribute__((address_space(1))) void*)g,
        (__attribute__((address_space(3))) void*)lds, 16, 0, 0);
}

// ---------------------------------------------------------------- gating ----
__global__ __launch_bounds__(64)
void gate_kernel(const float* __restrict__ x, const float* __restrict__ Wg,
                 const float* __restrict__ ebias,
                 float* __restrict__ rw, int* __restrict__ cnt,
                 int* __restrict__ toks,
                 int* __restrict__ se, int* __restrict__ sp, float* __restrict__ sw)
{
    const int n = blockIdx.x;
    const int lane = threadIdx.x;

    __shared__ float xs[C_DIM];
    ((float4*)xs)[lane] = ((const float4*)(x + (size_t)n * C_DIM))[lane];
    __syncthreads();

    float logit = -FLT_MAX;
    if (lane < E_RT) {
        float s = 0.f;
        #pragma unroll 4
        for (int c = 0; c < C_DIM; ++c)
            s = fmaf(xs[c], Wg[c * E_RT + lane], s);
        logit = s;
    }

    float m = logit;
    for (int off = 32; off; off >>= 1) m = fmaxf(m, __shfl_xor(m, off));
    float ev = (lane < E_RT) ? expf(logit - m) : 0.f;
    float sum = ev;
    for (int off = 32; off; off >>= 1) sum += __shfl_xor(sum, off);
    float gate = ev / sum;
    float biased = (lane < E_RT) ? gate + ebias[lane] : -FLT_MAX;

    float val[3]; int idx[3];
    float cur = biased;
    #pragma unroll
    for (int k = 0; k < 3; ++k) {
        float mk = cur;
        for (int off = 32; off; off >>= 1) mk = fmaxf(mk, __shfl_xor(mk, off));
        unsigned long long ball = __ballot(cur == mk && lane < E_RT);
        int sel = __ffsll(ball) - 1;
        val[k] = mk; idx[k] = sel;
        if (lane == sel) cur = -FLT_MAX;
    }

    float st = val[0] + val[1] + val[2];
    float wr0 = val[0] / st * 0.75f;
    float wr1 = val[1] / st * 0.75f;
    float wr2 = val[2] / st * 0.75f;

    if (lane < E_ALL) {
        float v = 0.f;
        if (lane == 0)          v = 0.25f;
        if (lane == idx[0] + 1) v = wr0;
        if (lane == idx[1] + 1) v = wr1;
        if (lane == idx[2] + 1) v = wr2;
        rw[(size_t)n * E_ALL + lane] = v;
    }

    if (lane == 0) {
        float wv[3] = {wr0, wr1, wr2};
        #pragma unroll
        for (int k = 0; k < 3; ++k) {
            int e31 = idx[k];
            int pos = atomicAdd(&cnt[e31], 1);
            toks[e31 * N_TOK + pos] = n;
            se[n * 3 + k] = e31;
            sp[n * 3 + k] = pos;
            sw[n * 3 + k] = wv[k];
        }
    }
}

__global__ void zero_cnt(int* cnt) { if (threadIdx.x < E_RT) cnt[threadIdx.x] = 0; }

// seg[0]=0 (shared rows); seg[e]=rowbase of routed expert e (1..31), 128-padded
__global__ void finalize(const int* __restrict__ cnt, int* __restrict__ seg) {
    if (threadIdx.x == 0) {
        int b = N_TOK;
        seg[0] = 0;
        for (int i = 0; i < E_RT; ++i) { seg[i + 1] = b; b += (cnt[i] + TN - 1) & ~(TN - 1); }
    }
}

// ----------------------------------------------- weight prep (LDS images) ---
// Wfc [E][C][H] f32 -> per step s: [r=32(h)][c=256] bf16, XOR-swizzled
__global__ __launch_bounds__(256)
void prep_fc(const float* __restrict__ Wfc, unsigned short* __restrict__ img)
{
    const int e = blockIdx.z;
    const int h0 = blockIdx.x * 32;
    const int c0 = blockIdx.y * 32;
    __shared__ float tb[32][33];
    const int tx = threadIdx.x, ty = threadIdx.y;
    #pragma unroll
    for (int i = ty; i < 32; i += 8)
        tb[i][tx] = Wfc[((size_t)e * C_DIM + c0 + i) * H_DIM + h0 + tx];
    __syncthreads();
    char* base = (char*)img + (size_t)e * (C_DIM * H_DIM * 2) + (h0 / HC2) * STEP_B;
    #pragma unroll
    for (int i = ty; i < 32; i += 8) {
        const int r = i, c = c0 + tx;                       // value = Wfc[c][h0+i]
        const int byte = (r * 512 + c * 2) ^ ((r & 7) << 4);
        *(unsigned short*)(base + byte) = f2bf(tb[tx][i]);
    }
}

// Wproj [E][H][C] f32 -> per step s: [cc=256][j=32(h)] bf16, XOR-swizzled
__global__ __launch_bounds__(256)
void prep_pj(const float* __restrict__ Wpj, unsigned short* __restrict__ img)
{
    const int e = blockIdx.z;
    const int h0 = blockIdx.x * 32;
    const int c0 = blockIdx.y * 32;
    __shared__ float tb[32][33];
    const int tx = threadIdx.x, ty = threadIdx.y;
    #pragma unroll
    for (int i = ty; i < 32; i += 8)
        tb[i][tx] = Wpj[((size_t)e * H_DIM + h0 + i) * C_DIM + c0 + tx];
    __syncthreads();
    char* base = (char*)img + (size_t)e * (C_DIM * H_DIM * 2) + (h0 / HC2) * STEP_B;
    #pragma unroll
    for (int i = ty; i < 32; i += 8) {
        const int cc = c0 + i, j = tx;                      // value = Wpj[h0+tx][cc]
        const int byte = (cc * 64 + j * 2) ^ ((cc & 7) << 4);
        *(unsigned short*)(base + byte) = f2bf(tb[tx][i]);
    }
}

// --------------------------------------------------------------- experts ----
__global__ __launch_bounds__(512, 4)
void expert_kernel(const float* __restrict__ x,
                   const unsigned short* __restrict__ wfc_img,
                   const unsigned short* __restrict__ wpj_img,
                   const int* __restrict__ cnt,
                   const int* __restrict__ seg,
                   const int* __restrict__ toks,
                   unsigned short* __restrict__ Yp)
{
    const int e = blockIdx.x;
    const int count = (e == 0) ? N_TOK : cnt[e - 1];
    const int start = blockIdx.y * TN;
    if (start >= count) return;
    const int rowbase = seg[e] + start;

    // static double buffers: DISTINCT objects so AA can prove
    // global_load_lds(next) does not alias ds_read(cur) -> true overlap
    __shared__ unsigned short Bs0[STEP_B / 2];
    __shared__ unsigned short Bs1[STEP_B / 2];
    __shared__ unsigned short Ps0[STEP_B / 2];
    __shared__ unsigned short Ps1[STEP_B / 2];
    __shared__ unsigned short Hs[TN * HC2];       // 8 KB, per-wave rows

    const int tid  = threadIdx.x;
    const int lane = tid & 63;
    const int w    = tid >> 6;        // 0..7, wave owns token rows w*16..+15
    const int l15  = lane & 15;
    const int kg   = lane >> 4;

    const int g = start + w * 16 + l15;
    int tok = 0;
    if (e == 0) tok = g;
    else if (g < count) tok = toks[(e - 1) * N_TOK + g];

    // A fragments (token row) in registers for all steps
    bf16x8 aF[8];
    const float* xr = x + (size_t)tok * C_DIM;
    #pragma unroll
    for (int ks = 0; ks < 8; ++ks) {
        const float4 u = *(const float4*)(xr + ks * 32 + kg * 8);
        const float4 v = *(const float4*)(xr + ks * 32 + kg * 8 + 4);
        bf16x8 a;
        a[0] = (short)f2bf(u.x); a[1] = (short)f2bf(u.y);
        a[2] = (short)f2bf(u.z); a[3] = (short)f2bf(u.w);
        a[4] = (short)f2bf(v.x); a[5] = (short)f2bf(v.y);
        a[6] = (short)f2bf(v.z); a[7] = (short)f2bf(v.w);
        aF[ks] = a;
    }

    f32x4 accP[16];
    #pragma unroll
    for (int i = 0; i < 16; ++i) accP[i] = (f32x4){0.f, 0.f, 0.f, 0.f};

    const char* gf = (const char*)wfc_img + (size_t)e * NST * STEP_B;
    const char* gp = (const char*)wpj_img + (size_t)e * NST * STEP_B;

    auto STAGE = [&](unsigned short* dB, unsigned short* dP, int s) {
        const char* srcF = gf + (size_t)s * STEP_B;
        const char* srcP = gp + (size_t)s * STEP_B;
        #pragma unroll
        for (int i = 0; i < 2; ++i) {                 // 512 thr x 16B x 2 = 16KB
            const int off = i * 8192 + tid * 16;
            gld16((char*)dB + off, srcF + off);
            gld16((char*)dP + off, srcP + off);
        }
    };

    auto COMPUTE = [&](const unsigned short* bB, const unsigned short* bP) {
        // ---- fc: 16 tok x 32 h, K=256
        f32x4 accF[2];
        accF[0] = (f32x4){0.f, 0.f, 0.f, 0.f};
        accF[1] = (f32x4){0.f, 0.f, 0.f, 0.f};
        #pragma unroll
        for (int ks = 0; ks < 8; ++ks) {
            const int cb = ks * 64 + kg * 16;
            #pragma unroll
            for (int ct = 0; ct < 2; ++ct) {
                const int r = ct * 16 + l15;
                const int byte = (r * 512 + cb) ^ ((r & 7) << 4);
                const bf16x8 b = *(const bf16x8*)((const char*)bB + byte);
                accF[ct] = __builtin_amdgcn_mfma_f32_16x16x32_bf16(aF[ks], b, accF[ct], 0, 0, 0);
            }
        }
        // ---- relu^2 -> Hs (wave-local rows, in-wave lgkm ordering)
        #pragma unroll
        for (int ct = 0; ct < 2; ++ct) {
            #pragma unroll
            for (int r = 0; r < 4; ++r) {
                const int hr = w * 16 + kg * 4 + r;
                float v = fmaxf(accF[ct][r], 0.f);
                v *= v;
                const int byte = (hr * 64 + (ct * 16 + l15) * 2) ^ ((hr & 7) << 4);
                *(unsigned short*)((char*)Hs + byte) = f2bf(v);
            }
        }
        // ---- proj: 16 tok x 256 c, K=32
        const int ar = w * 16 + l15;
        const int abyte = (ar * 64 + kg * 16) ^ ((ar & 7) << 4);
        const bf16x8 a = *(const bf16x8*)((const char*)Hs + abyte);
        #pragma unroll
        for (int ct = 0; ct < 16; ++ct) {
            const int cc = ct * 16 + l15;
            const int byte = (cc * 64 + kg * 16) ^ ((cc & 7) << 4);
            const bf16x8 b = *(const bf16x8*)((const char*)bP + byte);
            accP[ct] = __builtin_amdgcn_mfma_f32_16x16x32_bf16(a, b, accP[ct], 0, 0, 0);
        }
    };

    STAGE(Bs0, Ps0, 0);
    asm volatile("s_waitcnt vmcnt(0)" ::: "memory");
    __syncthreads();

    #pragma unroll 1
    for (int s = 0; s < NST; s += 2) {
        // phase A: prefetch -> buf1, compute buf0
        if (s + 1 < NST) STAGE(Bs1, Ps1, s + 1);
        COMPUTE(Bs0, Ps0);
        asm volatile("s_waitcnt vmcnt(0)" ::: "memory");
        __syncthreads();
        // phase B: prefetch -> buf0, compute buf1
        if (s + 2 < NST) STAGE(Bs0, Ps0, s + 2);
        if (s + 1 < NST) COMPUTE(Bs1, Ps1);
        asm volatile("s_waitcnt vmcnt(0)" ::: "memory");
        __syncthreads();
    }

    // ---- plain store of unweighted partials to own Yp rows ----
    #pragma unroll
    for (int ct = 0; ct < 16; ++ct) {
        #pragma unroll
        for (int r = 0; r < 4; ++r) {
            const int m = w * 16 + kg * 4 + r;
            Yp[(size_t)(rowbase + m) * C_DIM + ct * 16 + l15] = f2bf(accP[ct][r]);
        }
    }
}

// --------------------------------------------------------------- combine ----
__global__ __launch_bounds__(256)
void combine_kernel(const unsigned short* __restrict__ Yp,
                    const int* __restrict__ seg,
                    const int* __restrict__ se, const int* __restrict__ sp,
                    const float* __restrict__ sw,
                    float* __restrict__ out)
{
    const int t = blockIdx.x * 256 + threadIdx.x;   // 262144 threads
    const int n = t >> 5;
    const int c0 = (t & 31) * 8;

    float acc[8];
    {
        const bf16x8 y = *(const bf16x8*)(Yp + (size_t)n * C_DIM + c0);
        #pragma unroll
        for (int i = 0; i < 8; ++i) acc[i] = 0.25f * bf2f((unsigned short)y[i]);
    }
    #pragma unroll
    for (int k = 0; k < 3; ++k) {
        const int e = se[n * 3 + k];
        const int row = seg[e + 1] + sp[n * 3 + k];
        const float wgt = sw[n * 3 + k];
        const bf16x8 y = *(const bf16x8*)(Yp + (size_t)row * C_DIM + c0);
        #pragma unroll
        for (int i = 0; i < 8; ++i) acc[i] = fmaf(wgt, bf2f((unsigned short)y[i]), acc[i]);
    }
    float4 o0 = make_float4(acc[0], acc[1], acc[2], acc[3]);
    float4 o1 = make_float4(acc[4], acc[5], acc[6], acc[7]);
    *(float4*)(out + (size_t)n * C_DIM + c0)     = o0;
    *(float4*)(out + (size_t)n * C_DIM + c0 + 4) = o1;
}

// ---------------------------------------------------------------- launch ----
extern "C" void kernel_launch(void* const* d_in, const int* in_sizes, int n_in,
                              void* d_out, int out_size, void* d_ws, size_t ws_size,
                              hipStream_t stream) {
    const float* x     = (const float*)d_in[0];
    const float* Wg    = (const float*)d_in[1];
    const float* Wfc   = (const float*)d_in[2];
    const float* Wpj   = (const float*)d_in[3];
    const float* ebias = (const float*)d_in[4];

    float* out = (float*)d_out;                       // [N, C]
    float* rw  = out + (size_t)N_TOK * C_DIM;         // [N, 32]

    char* ws = (char*)d_ws;
    int*   cnt  = (int*)ws;                                        ws += 256;
    int*   seg  = (int*)ws;                                        ws += 256;
    int*   toks = (int*)ws;                                        ws += (size_t)E_RT * N_TOK * 4;
    int*   se   = (int*)ws;                                        ws += (size_t)N_TOK * 3 * 4;
    int*   sp   = (int*)ws;                                        ws += (size_t)N_TOK * 3 * 4;
    float* sw   = (float*)ws;                                      ws += (size_t)N_TOK * 3 * 4;
    unsigned short* wfc_img = (unsigned short*)ws;                 ws += (size_t)E_ALL * C_DIM * H_DIM * 2;
    unsigned short* wpj_img = (unsigned short*)ws;                 ws += (size_t)E_ALL * C_DIM * H_DIM * 2;
    unsigned short* Yp      = (unsigned short*)ws;

    zero_cnt<<<1, 64, 0, stream>>>(cnt);
    prep_fc<<<dim3(H_DIM / 32, C_DIM / 32, E_ALL), dim3(32, 8), 0, stream>>>(Wfc, wfc_img);
    prep_pj<<<dim3(H_DIM / 32, C_DIM / 32, E_ALL), dim3(32, 8), 0, stream>>>(Wpj, wpj_img);
    gate_kernel<<<N_TOK, 64, 0, stream>>>(x, Wg, ebias, rw, cnt, toks, se, sp, sw);
    finalize<<<1, 64, 0, stream>>>(cnt, seg);
    expert_kernel<<<dim3(E_ALL, N_TOK / TN), 512, 0, stream>>>(
        x, wfc_img, wpj_img, cnt, seg, toks, Yp);
    combine_kernel<<<(N_TOK * 32) / 256, 256, 0, stream>>>(Yp, seg, se, sp, sw, out);
}

// Round 6
// 807.431 us; speedup vs baseline: 1.7687x; 1.7687x over previous
//
#include <hip/hip_runtime.h>
#include <hip/hip_bf16.h>
#include <cfloat>

#define N_TOK 8192
#define C_DIM 256
#define H_DIM 1024
#define E_ALL 32
#define E_RT  31
#define HS    128                     // h per slice
#define NSL   8                       // slices
#define NPAIR 4                       // slice-pairs (Yp slots)
#define CHUNK 512                     // tokens per block
#define MAXCH (N_TOK / CHUNK)         // 16
#define TILE  64                      // tokens per tile (4 waves x 16)
#define SLICE_B (HS * C_DIM * 2)      // 64 KB per weight slice

typedef __attribute__((ext_vector_type(8))) short bf16x8;
typedef __attribute__((ext_vector_type(4))) float f32x4;

__device__ __forceinline__ unsigned short f2bf(float f) {
    return __builtin_bit_cast(unsigned short, __float2bfloat16(f));
}
__device__ __forceinline__ float bf2f(unsigned short u) {
    unsigned int x = ((unsigned int)u) << 16;
    return __builtin_bit_cast(float, x);
}
__device__ __forceinline__ void gld16(void* lds, const void* g) {
    __builtin_amdgcn_global_load_lds(
        (const __attribute__((address_space(1))) void*)g,
        (__attribute__((address_space(3))) void*)lds, 16, 0, 0);
}

// ---------------------------------------------------------------- gating ----
__global__ __launch_bounds__(64)
void gate_kernel(const float* __restrict__ x, const float* __restrict__ Wg,
                 const float* __restrict__ ebias,
                 float* __restrict__ rw, int* __restrict__ cnt,
                 int* __restrict__ toks,
                 int* __restrict__ se, int* __restrict__ sp, float* __restrict__ sw)
{
    const int n = blockIdx.x;
    const int lane = threadIdx.x;

    __shared__ float xs[C_DIM];
    ((float4*)xs)[lane] = ((const float4*)(x + (size_t)n * C_DIM))[lane];
    __syncthreads();

    float logit = -FLT_MAX;
    if (lane < E_RT) {
        float s = 0.f;
        #pragma unroll 4
        for (int c = 0; c < C_DIM; ++c)
            s = fmaf(xs[c], Wg[c * E_RT + lane], s);
        logit = s;
    }

    float m = logit;
    for (int off = 32; off; off >>= 1) m = fmaxf(m, __shfl_xor(m, off));
    float ev = (lane < E_RT) ? expf(logit - m) : 0.f;
    float sum = ev;
    for (int off = 32; off; off >>= 1) sum += __shfl_xor(sum, off);
    float gate = ev / sum;
    float biased = (lane < E_RT) ? gate + ebias[lane] : -FLT_MAX;

    float val[3]; int idx[3];
    float cur = biased;
    #pragma unroll
    for (int k = 0; k < 3; ++k) {
        float mk = cur;
        for (int off = 32; off; off >>= 1) mk = fmaxf(mk, __shfl_xor(mk, off));
        unsigned long long ball = __ballot(cur == mk && lane < E_RT);
        int sel = __ffsll(ball) - 1;
        val[k] = mk; idx[k] = sel;
        if (lane == sel) cur = -FLT_MAX;
    }

    float st = val[0] + val[1] + val[2];
    float wr0 = val[0] / st * 0.75f;
    float wr1 = val[1] / st * 0.75f;
    float wr2 = val[2] / st * 0.75f;

    if (lane < E_ALL) {
        float v = 0.f;
        if (lane == 0)          v = 0.25f;
        if (lane == idx[0] + 1) v = wr0;
        if (lane == idx[1] + 1) v = wr1;
        if (lane == idx[2] + 1) v = wr2;
        rw[(size_t)n * E_ALL + lane] = v;
    }

    if (lane == 0) {
        float wv[3] = {wr0, wr1, wr2};
        #pragma unroll
        for (int k = 0; k < 3; ++k) {
            int e31 = idx[k];
            int pos = atomicAdd(&cnt[e31], 1);
            toks[e31 * N_TOK + pos] = n;
            se[n * 3 + k] = e31;
            sp[n * 3 + k] = pos;
            sw[n * 3 + k] = wv[k];
        }
    }
}

__global__ void zero_cnt(int* cnt) { if (threadIdx.x < E_RT) cnt[threadIdx.x] = 0; }

// seg[0]=0 (shared rows); seg[e31+1]=rowbase of routed expert e31, 64-padded
__global__ void finalize(const int* __restrict__ cnt, int* __restrict__ seg) {
    if (threadIdx.x == 0) {
        int b = N_TOK;
        seg[0] = 0;
        for (int i = 0; i < E_RT; ++i) { seg[i + 1] = b; b += (cnt[i] + 63) & ~63; }
    }
}

// -------------------------------------------------------------- x -> bf16 ---
__global__ __launch_bounds__(256)
void prep_x(const float* __restrict__ x, unsigned short* __restrict__ xb)
{
    const int t = blockIdx.x * 256 + threadIdx.x;
    const float4 v = ((const float4*)x)[t];
    ushort4 b;
    b.x = f2bf(v.x); b.y = f2bf(v.y); b.z = f2bf(v.z); b.w = f2bf(v.w);
    ((ushort4*)xb)[t] = b;
}

// -------------------------------------- weight prep: MFMA-fragment images ---
// fc image per (e,s): 64 lines (ks=0..7, ct=0..7); line = 64 lanes x 8 bf16:
//   value(lane=(l15,kg), j) = Wfc[e][c = ks*32+kg*8+j][h = s*128 + ct*16 + l15]
__global__ __launch_bounds__(256)
void prep_fc(const float* __restrict__ Wfc, unsigned short* __restrict__ img)
{
    const int s = blockIdx.x, e = blockIdx.y;
    const int h0 = s * HS;
    __shared__ unsigned short tb[C_DIM * HS];     // [c][hh] bf16, 64 KB
    const int tid = threadIdx.x;
    #pragma unroll
    for (int i = 0; i < 32; ++i) {
        const int fidx = i * 1024 + tid * 4;
        const int c = fidx >> 7, hh = fidx & 127;
        const float4 v = *(const float4*)(Wfc + ((size_t)e * C_DIM + c) * H_DIM + h0 + hh);
        ushort4 b;
        b.x = f2bf(v.x); b.y = f2bf(v.y); b.z = f2bf(v.z); b.w = f2bf(v.w);
        *(ushort4*)(tb + c * HS + hh) = b;
    }
    __syncthreads();
    const int lane = tid & 63, w = tid >> 6;
    const int l15 = lane & 15, kg = lane >> 4;
    unsigned short* dst = img + ((size_t)e * NSL + s) * (SLICE_B / 2);
    for (int li = w; li < 64; li += 4) {
        const int ks = li >> 3, ct = li & 7;
        bf16x8 v;
        #pragma unroll
        for (int j = 0; j < 8; ++j)
            v[j] = (short)tb[(ks * 32 + kg * 8 + j) * HS + ct * 16 + l15];
        *(bf16x8*)(dst + (size_t)li * 512 + lane * 8) = v;
    }
}

// pj image per (e,s): 64 lines (ks=0..3, ct=0..15):
//   value(lane, j) = Wpj[e][h = s*128 + ks*32+kg*8+j][cc = ct + l15*16]
__global__ __launch_bounds__(256)
void prep_pj(const float* __restrict__ Wpj, unsigned short* __restrict__ img)
{
    const int s = blockIdx.x, e = blockIdx.y;
    const int h0 = s * HS;
    __shared__ unsigned short tb[HS * C_DIM];     // [r(h)][cc] bf16, 64 KB
    const int tid = threadIdx.x;
    #pragma unroll
    for (int i = 0; i < 32; ++i) {
        const int fidx = i * 1024 + tid * 4;
        const int r = fidx >> 8, cc = fidx & 255;
        const float4 v = *(const float4*)(Wpj + ((size_t)e * H_DIM + h0 + r) * C_DIM + cc);
        ushort4 b;
        b.x = f2bf(v.x); b.y = f2bf(v.y); b.z = f2bf(v.z); b.w = f2bf(v.w);
        *(ushort4*)(tb + r * C_DIM + cc) = b;
    }
    __syncthreads();
    const int lane = tid & 63, w = tid >> 6;
    const int l15 = lane & 15, kg = lane >> 4;
    unsigned short* dst = img + ((size_t)e * NSL + s) * (SLICE_B / 2);
    for (int li = w; li < 64; li += 4) {
        const int ks = li >> 4, ct = li & 15;
        bf16x8 v;
        #pragma unroll
        for (int j = 0; j < 8; ++j)
            v[j] = (short)tb[(ks * 32 + kg * 8 + j) * C_DIM + ct + l15 * 16];
        *(bf16x8*)(dst + (size_t)li * 512 + lane * 8) = v;
    }
}

// ------------------------------------------------- weight-stationary expert -
struct AFrag { bf16x8 k[8]; };

__global__ __launch_bounds__(256)
void expert_kernel(const unsigned short* __restrict__ xb,
                   const unsigned short* __restrict__ fc_img,
                   const unsigned short* __restrict__ pj_img,
                   const int* __restrict__ cnt,
                   const int* __restrict__ seg,
                   const int* __restrict__ toks,
                   unsigned short* __restrict__ Yp)
{
    const int e    = blockIdx.x >> 4;           // MAXCH = 16
    const int ch   = blockIdx.x & 15;
    const int pair = blockIdx.y;                // 0..3
    const int count = (e == 0) ? N_TOK : cnt[e - 1];
    const int tstart = ch * CHUNK;
    if (tstart >= count) return;
    const int tend = min(tstart + CHUNK, count);
    const int segbase = seg[e];

    __shared__ unsigned short fcS[SLICE_B / 2];   // 64 KB
    __shared__ unsigned short pjS[SLICE_B / 2];   // 64 KB
    __shared__ unsigned short Hs[4 * 16 * HS];    // 16 KB (per-wave 4 KB)

    const int tid  = threadIdx.x;
    const int lane = tid & 63;
    const int w    = tid >> 6;
    const int l15  = lane & 15;
    const int kg   = lane >> 4;

    auto STAGE = [&](unsigned short* dst, const char* src) {   // 64 KB linear
        #pragma unroll
        for (int i = 0; i < 16; ++i) {
            const int off = i * 4096 + tid * 16;
            gld16((char*)dst + off, src + off);
        }
    };

    auto loadA = [&](int t0) -> AFrag {
        AFrag a;
        const int p = t0 + w * 16 + l15;
        int tok = 0;
        if (p < tend) tok = (e == 0) ? p : toks[(e - 1) * N_TOK + p];
        const unsigned short* xr = xb + (size_t)tok * C_DIM + kg * 8;
        #pragma unroll
        for (int ks = 0; ks < 8; ++ks)
            a.k[ks] = *(const bf16x8*)(xr + ks * 32);
        return a;
    };

    auto doTile = [&](int t0, const AFrag& a, bool rmw) {
        // ---- fc: 16 tok x 128 h (K=256), frag-order B reads (conflict-free)
        f32x4 accF[8];
        #pragma unroll
        for (int i = 0; i < 8; ++i) accF[i] = (f32x4){0.f, 0.f, 0.f, 0.f};
        #pragma unroll
        for (int ks = 0; ks < 8; ++ks) {
            #pragma unroll
            for (int ct = 0; ct < 8; ++ct) {
                const bf16x8 b = *(const bf16x8*)((const char*)fcS +
                                   (((ks * 8 + ct) * 64 + lane) << 4));
                accF[ct] = __builtin_amdgcn_mfma_f32_16x16x32_bf16(a.k[ks], b, accF[ct], 0, 0, 0);
            }
        }
        // ---- relu^2 -> Hs (wave-private region, swizzled rows)
        char* hbase = (char*)Hs + w * 4096;
        #pragma unroll
        for (int ct = 0; ct < 8; ++ct) {
            #pragma unroll
            for (int r = 0; r < 4; ++r) {
                const int hr = kg * 4 + r;                 // token row 0..15
                float v = fmaxf(accF[ct][r], 0.f);
                v *= v;
                const int byte = (hr * 256 + (ct * 16 + l15) * 2) ^ ((hr & 7) << 4);
                *(unsigned short*)(hbase + byte) = f2bf(v);
            }
        }
        // ---- proj: 16 tok x 256 cc (K=128); lane owns cc = l15*16 + ct
        f32x4 accP[16];
        #pragma unroll
        for (int i = 0; i < 16; ++i) accP[i] = (f32x4){0.f, 0.f, 0.f, 0.f};
        #pragma unroll
        for (int ks = 0; ks < 4; ++ks) {
            const int abyte = (l15 * 256 + ks * 64 + kg * 16) ^ ((l15 & 7) << 4);
            const bf16x8 av = *(const bf16x8*)(hbase + abyte);
            #pragma unroll
            for (int ct = 0; ct < 16; ++ct) {
                const bf16x8 b = *(const bf16x8*)((const char*)pjS +
                                   (((ks * 16 + ct) * 64 + lane) << 4));
                accP[ct] = __builtin_amdgcn_mfma_f32_16x16x32_bf16(av, b, accP[ct], 0, 0, 0);
            }
        }
        // ---- coalesced store/rmw: lane writes 16 consecutive cc (32 B)
        #pragma unroll
        for (int r = 0; r < 4; ++r) {
            const int p = t0 + w * 16 + kg * 4 + r;
            if (p < tend) {
                unsigned short* dst = Yp + (((size_t)(segbase + p)) * NPAIR + pair) * C_DIM + l15 * 16;
                bf16x8 u0, u1;
                if (rmw) {
                    const bf16x8 o0 = *(const bf16x8*)dst;
                    const bf16x8 o1 = *(const bf16x8*)(dst + 8);
                    #pragma unroll
                    for (int j = 0; j < 8; ++j) {
                        u0[j] = (short)f2bf(accP[j][r]     + bf2f((unsigned short)o0[j]));
                        u1[j] = (short)f2bf(accP[j + 8][r] + bf2f((unsigned short)o1[j]));
                    }
                } else {
                    #pragma unroll
                    for (int j = 0; j < 8; ++j) {
                        u0[j] = (short)f2bf(accP[j][r]);
                        u1[j] = (short)f2bf(accP[j + 8][r]);
                    }
                }
                *(bf16x8*)dst       = u0;
                *(bf16x8*)(dst + 8) = u1;
            }
        }
    };

    #pragma unroll 1
    for (int half = 0; half < 2; ++half) {
        const int s = pair * 2 + half;
        if (half) __syncthreads();              // all waves done with prev slice
        STAGE(fcS, (const char*)fc_img + ((size_t)e * NSL + s) * SLICE_B);
        STAGE(pjS, (const char*)pj_img + ((size_t)e * NSL + s) * SLICE_B);
        asm volatile("s_waitcnt vmcnt(0)" ::: "memory");
        __syncthreads();

        AFrag a = loadA(tstart);
        #pragma unroll 1
        for (int t0 = tstart; t0 < tend; t0 += TILE) {
            AFrag an;
            if (t0 + TILE < tend) an = loadA(t0 + TILE);   // prefetch next tile
            doTile(t0, a, half != 0);
            a = an;
        }
    }
}

// --------------------------------------------------------------- combine ----
__global__ __launch_bounds__(256)
void combine_kernel(const unsigned short* __restrict__ Yp,
                    const int* __restrict__ seg,
                    const int* __restrict__ se, const int* __restrict__ sp,
                    const float* __restrict__ sw,
                    float* __restrict__ out)
{
    const int t = blockIdx.x * 256 + threadIdx.x;
    const int n = t >> 5;
    const int c0 = (t & 31) * 8;

    float acc[8];
    #pragma unroll
    for (int i = 0; i < 8; ++i) acc[i] = 0.f;

    const unsigned short* b0 = Yp + ((size_t)n * NPAIR) * C_DIM + c0;
    #pragma unroll
    for (int p = 0; p < NPAIR; ++p) {
        const bf16x8 y = *(const bf16x8*)(b0 + p * C_DIM);
        #pragma unroll
        for (int i = 0; i < 8; ++i) acc[i] = fmaf(0.25f, bf2f((unsigned short)y[i]), acc[i]);
    }
    #pragma unroll
    for (int k = 0; k < 3; ++k) {
        const int e = se[n * 3 + k];
        const int row = seg[e + 1] + sp[n * 3 + k];
        const float wgt = sw[n * 3 + k];
        const unsigned short* bb = Yp + ((size_t)row * NPAIR) * C_DIM + c0;
        #pragma unroll
        for (int p = 0; p < NPAIR; ++p) {
            const bf16x8 y = *(const bf16x8*)(bb + p * C_DIM);
            #pragma unroll
            for (int i = 0; i < 8; ++i) acc[i] = fmaf(wgt, bf2f((unsigned short)y[i]), acc[i]);
        }
    }
    float4 o0 = make_float4(acc[0], acc[1], acc[2], acc[3]);
    float4 o1 = make_float4(acc[4], acc[5], acc[6], acc[7]);
    *(float4*)(out + (size_t)n * C_DIM + c0)     = o0;
    *(float4*)(out + (size_t)n * C_DIM + c0 + 4) = o1;
}

// ---------------------------------------------------------------- launch ----
extern "C" void kernel_launch(void* const* d_in, const int* in_sizes, int n_in,
                              void* d_out, int out_size, void* d_ws, size_t ws_size,
                              hipStream_t stream) {
    const float* x     = (const float*)d_in[0];
    const float* Wg    = (const float*)d_in[1];
    const float* Wfc   = (const float*)d_in[2];
    const float* Wpj   = (const float*)d_in[3];
    const float* ebias = (const float*)d_in[4];

    float* out = (float*)d_out;                       // [N, C]
    float* rw  = out + (size_t)N_TOK * C_DIM;         // [N, 32]

    char* ws = (char*)d_ws;
    int*   cnt  = (int*)ws;                                        ws += 256;
    int*   seg  = (int*)ws;                                        ws += 256;
    int*   toks = (int*)ws;                                        ws += (size_t)E_RT * N_TOK * 4;
    int*   se   = (int*)ws;                                        ws += (size_t)N_TOK * 3 * 4;
    int*   sp   = (int*)ws;                                        ws += (size_t)N_TOK * 3 * 4;
    float* sw   = (float*)ws;                                      ws += (size_t)N_TOK * 3 * 4;
    unsigned short* xb      = (unsigned short*)ws;                 ws += (size_t)N_TOK * C_DIM * 2;
    unsigned short* fc_img  = (unsigned short*)ws;                 ws += (size_t)E_ALL * C_DIM * H_DIM * 2;
    unsigned short* pj_img  = (unsigned short*)ws;                 ws += (size_t)E_ALL * C_DIM * H_DIM * 2;
    unsigned short* Yp      = (unsigned short*)ws;                 // [<=34944][4][256] bf16 ~72 MB

    zero_cnt<<<1, 64, 0, stream>>>(cnt);
    prep_x<<<(N_TOK * C_DIM / 4) / 256, 256, 0, stream>>>(x, xb);
    prep_fc<<<dim3(NSL, E_ALL), 256, 0, stream>>>(Wfc, fc_img);
    prep_pj<<<dim3(NSL, E_ALL), 256, 0, stream>>>(Wpj, pj_img);
    gate_kernel<<<N_TOK, 64, 0, stream>>>(x, Wg, ebias, rw, cnt, toks, se, sp, sw);
    finalize<<<1, 64, 0, stream>>>(cnt, seg);
    expert_kernel<<<dim3(E_ALL * MAXCH, NPAIR), 256, 0, stream>>>(
        xb, fc_img, pj_img, cnt, seg, toks, Yp);
    combine_kernel<<<(N_TOK * 32) / 256, 256, 0, stream>>>(Yp, seg, se, sp, sw, out);
}

// Round 7
// 522.169 us; speedup vs baseline: 2.7349x; 1.5463x over previous
//
#include <hip/hip_runtime.h>
#include <hip/hip_bf16.h>
#include <cfloat>

#define N_TOK 8192
#define C_DIM 256
#define H_DIM 1024
#define E_ALL 32
#define E_RT  31
#define HS    128                     // h per image slice (prep granularity)
#define NSL   8                       // slices
#define TN    64                      // tokens per block (4 waves x 16)
#define HC2   32                      // h per step
#define NST   (H_DIM / HC2)           // 32 steps
#define STEP_B16 16384                // bytes per weight-matrix step chunk
#define SLICE_B (HS * C_DIM * 2)      // 64 KB per slice

typedef __attribute__((ext_vector_type(8))) short bf16x8;
typedef __attribute__((ext_vector_type(4))) float f32x4;

__device__ __forceinline__ unsigned short f2bf(float f) {
    return __builtin_bit_cast(unsigned short, __float2bfloat16(f));
}
__device__ __forceinline__ float bf2f(unsigned short u) {
    unsigned int x = ((unsigned int)u) << 16;
    return __builtin_bit_cast(float, x);
}
__device__ __forceinline__ void gld16(void* lds, const void* g) {
    __builtin_amdgcn_global_load_lds(
        (const __attribute__((address_space(1))) void*)g,
        (__attribute__((address_space(3))) void*)lds, 16, 0, 0);
}

// ---------------------------------------------------------------- gating ----
__global__ __launch_bounds__(64)
void gate_kernel(const float* __restrict__ x, const float* __restrict__ Wg,
                 const float* __restrict__ ebias,
                 float* __restrict__ rw, int* __restrict__ cnt,
                 int* __restrict__ toks,
                 int* __restrict__ se, int* __restrict__ sp, float* __restrict__ sw)
{
    const int n = blockIdx.x;
    const int lane = threadIdx.x;

    __shared__ float xs[C_DIM];
    ((float4*)xs)[lane] = ((const float4*)(x + (size_t)n * C_DIM))[lane];
    __syncthreads();

    float logit = -FLT_MAX;
    if (lane < E_RT) {
        float s = 0.f;
        #pragma unroll 4
        for (int c = 0; c < C_DIM; ++c)
            s = fmaf(xs[c], Wg[c * E_RT + lane], s);
        logit = s;
    }

    float m = logit;
    for (int off = 32; off; off >>= 1) m = fmaxf(m, __shfl_xor(m, off));
    float ev = (lane < E_RT) ? expf(logit - m) : 0.f;
    float sum = ev;
    for (int off = 32; off; off >>= 1) sum += __shfl_xor(sum, off);
    float gate = ev / sum;
    float biased = (lane < E_RT) ? gate + ebias[lane] : -FLT_MAX;

    float val[3]; int idx[3];
    float cur = biased;
    #pragma unroll
    for (int k = 0; k < 3; ++k) {
        float mk = cur;
        for (int off = 32; off; off >>= 1) mk = fmaxf(mk, __shfl_xor(mk, off));
        unsigned long long ball = __ballot(cur == mk && lane < E_RT);
        int sel = __ffsll(ball) - 1;
        val[k] = mk; idx[k] = sel;
        if (lane == sel) cur = -FLT_MAX;
    }

    float st = val[0] + val[1] + val[2];
    float wr0 = val[0] / st * 0.75f;
    float wr1 = val[1] / st * 0.75f;
    float wr2 = val[2] / st * 0.75f;

    if (lane < E_ALL) {
        float v = 0.f;
        if (lane == 0)          v = 0.25f;
        if (lane == idx[0] + 1) v = wr0;
        if (lane == idx[1] + 1) v = wr1;
        if (lane == idx[2] + 1) v = wr2;
        rw[(size_t)n * E_ALL + lane] = v;
    }

    if (lane == 0) {
        float wv[3] = {wr0, wr1, wr2};
        #pragma unroll
        for (int k = 0; k < 3; ++k) {
            int e31 = idx[k];
            int pos = atomicAdd(&cnt[e31], 1);
            toks[e31 * N_TOK + pos] = n;
            se[n * 3 + k] = e31;
            sp[n * 3 + k] = pos;
            sw[n * 3 + k] = wv[k];
        }
    }
}

__global__ void zero_cnt(int* cnt) { if (threadIdx.x < E_RT) cnt[threadIdx.x] = 0; }

// seg[0]=0 (shared rows); seg[e31+1]=rowbase of routed expert e31, 64-padded
__global__ void finalize(const int* __restrict__ cnt, int* __restrict__ seg) {
    if (threadIdx.x == 0) {
        int b = N_TOK;
        seg[0] = 0;
        for (int i = 0; i < E_RT; ++i) { seg[i + 1] = b; b += (cnt[i] + 63) & ~63; }
    }
}

// -------------------------------------------------------------- x -> bf16 ---
__global__ __launch_bounds__(256)
void prep_x(const float* __restrict__ x, unsigned short* __restrict__ xb)
{
    const int t = blockIdx.x * 256 + threadIdx.x;
    const float4 v = ((const float4*)x)[t];
    ushort4 b;
    b.x = f2bf(v.x); b.y = f2bf(v.y); b.z = f2bf(v.z); b.w = f2bf(v.w);
    ((ushort4*)xb)[t] = b;
}

// -------------------------------------- weight prep: MFMA-fragment images ---
// fc image per (e,s): 64 lines, CT-MAJOR (li = ct*8 + ks); line = 64 lanes x 16B:
//   value(lane=(l15,kg), j) = Wfc[e][c = ks*32+kg*8+j][h = s*128 + ct*16 + l15]
// => image is linear in step t (= s*4 + ct/2): step chunk = base + t*16384.
__global__ __launch_bounds__(256)
void prep_fc(const float* __restrict__ Wfc, unsigned short* __restrict__ img)
{
    const int s = blockIdx.x, e = blockIdx.y;
    const int h0 = s * HS;
    __shared__ unsigned short tb[C_DIM * HS];     // [c][hh] bf16, 64 KB
    const int tid = threadIdx.x;
    #pragma unroll
    for (int i = 0; i < 32; ++i) {
        const int fidx = i * 1024 + tid * 4;
        const int c = fidx >> 7, hh = fidx & 127;
        const float4 v = *(const float4*)(Wfc + ((size_t)e * C_DIM + c) * H_DIM + h0 + hh);
        ushort4 b;
        b.x = f2bf(v.x); b.y = f2bf(v.y); b.z = f2bf(v.z); b.w = f2bf(v.w);
        *(ushort4*)(tb + c * HS + hh) = b;
    }
    __syncthreads();
    const int lane = tid & 63, w = tid >> 6;
    const int l15 = lane & 15, kg = lane >> 4;
    unsigned short* dst = img + ((size_t)e * NSL + s) * (SLICE_B / 2);
    for (int li = w; li < 64; li += 4) {
        const int ct = li >> 3, ks = li & 7;      // ct-major
        bf16x8 v;
        #pragma unroll
        for (int j = 0; j < 8; ++j)
            v[j] = (short)tb[(ks * 32 + kg * 8 + j) * HS + ct * 16 + l15];
        *(bf16x8*)(dst + (size_t)li * 512 + lane * 8) = v;
    }
}

// pj image per (e,s): 64 lines, KS-MAJOR (li = ks*16 + ct):
//   value(lane, j) = Wpj[e][h = s*128 + ks*32 + kg*8 + j][cc = ct + l15*16]
// => step t (= s*4 + ks): chunk = base + t*16384, local line = ct.
__global__ __launch_bounds__(256)
void prep_pj(const float* __restrict__ Wpj, unsigned short* __restrict__ img)
{
    const int s = blockIdx.x, e = blockIdx.y;
    const int h0 = s * HS;
    __shared__ unsigned short tb[HS * C_DIM];     // [r(h)][cc] bf16, 64 KB
    const int tid = threadIdx.x;
    #pragma unroll
    for (int i = 0; i < 32; ++i) {
        const int fidx = i * 1024 + tid * 4;
        const int r = fidx >> 8, cc = fidx & 255;
        const float4 v = *(const float4*)(Wpj + ((size_t)e * H_DIM + h0 + r) * C_DIM + cc);
        ushort4 b;
        b.x = f2bf(v.x); b.y = f2bf(v.y); b.z = f2bf(v.z); b.w = f2bf(v.w);
        *(ushort4*)(tb + r * C_DIM + cc) = b;
    }
    __syncthreads();
    const int lane = tid & 63, w = tid >> 6;
    const int l15 = lane & 15, kg = lane >> 4;
    unsigned short* dst = img + ((size_t)e * NSL + s) * (SLICE_B / 2);
    for (int li = w; li < 64; li += 4) {
        const int ks = li >> 4, ct = li & 15;
        bf16x8 v;
        #pragma unroll
        for (int j = 0; j < 8; ++j)
            v[j] = (short)tb[(ks * 32 + kg * 8 + j) * C_DIM + ct + l15 * 16];
        *(bf16x8*)(dst + (size_t)li * 512 + lane * 8) = v;
    }
}

// --------------------------------------------------------------- experts ----
__global__ __launch_bounds__(256)
void expert_kernel(const unsigned short* __restrict__ xb,
                   const unsigned short* __restrict__ fc_img,
                   const unsigned short* __restrict__ pj_img,
                   const int* __restrict__ cnt,
                   const int* __restrict__ seg,
                   const int* __restrict__ toks,
                   unsigned short* __restrict__ Yp)
{
    const int e = blockIdx.x;
    const int count = (e == 0) ? N_TOK : cnt[e - 1];
    const int tstart = blockIdx.y * TN;
    if (tstart >= count) return;
    const int tend = min(tstart + TN, count);
    const int segbase = seg[e];

    // static double buffers (distinct objects -> no alias-forced vmcnt drains)
    __shared__ unsigned short fc0[STEP_B16 / 2];
    __shared__ unsigned short fc1[STEP_B16 / 2];
    __shared__ unsigned short pj0[STEP_B16 / 2];
    __shared__ unsigned short pj1[STEP_B16 / 2];
    __shared__ unsigned short Hs[TN * HC2];       // 4 KB, wave-local rows

    const int tid  = threadIdx.x;
    const int lane = tid & 63;
    const int w    = tid >> 6;
    const int l15  = lane & 15;
    const int kg   = lane >> 4;

    // my token (A-row = w*16 + l15)
    const int p = tstart + w * 16 + l15;
    int tok = 0;
    if (p < tend) tok = (e == 0) ? p : toks[(e - 1) * N_TOK + p];

    // A fragments in registers for all steps
    bf16x8 aF[8];
    const unsigned short* xr = xb + (size_t)tok * C_DIM + kg * 8;
    #pragma unroll
    for (int ks = 0; ks < 8; ++ks)
        aF[ks] = *(const bf16x8*)(xr + ks * 32);

    f32x4 accP[16];
    #pragma unroll
    for (int i = 0; i < 16; ++i) accP[i] = (f32x4){0.f, 0.f, 0.f, 0.f};

    const char* fsrc = (const char*)fc_img + (size_t)e * NSL * SLICE_B;
    const char* psrc = (const char*)pj_img + (size_t)e * NSL * SLICE_B;

    auto STAGE16 = [&](unsigned short* dst, const char* src) {  // 16 KB linear
        #pragma unroll
        for (int i = 0; i < 4; ++i) {
            const int off = i * 4096 + tid * 16;
            gld16((char*)dst + off, src + off);
        }
    };

    auto COMPUTE = [&](const unsigned short* bF, const unsigned short* bP) {
        // ---- fc: 16 tok x 32 h, K=256; B reads conflict-free (line*1KB+lane*16)
        f32x4 accF[2];
        accF[0] = (f32x4){0.f, 0.f, 0.f, 0.f};
        accF[1] = (f32x4){0.f, 0.f, 0.f, 0.f};
        #pragma unroll
        for (int ks = 0; ks < 8; ++ks) {
            #pragma unroll
            for (int ct = 0; ct < 2; ++ct) {
                const bf16x8 b = *(const bf16x8*)((const char*)bF +
                                   (((ct * 8 + ks) * 64 + lane) << 4));
                accF[ct] = __builtin_amdgcn_mfma_f32_16x16x32_bf16(aF[ks], b, accF[ct], 0, 0, 0);
            }
        }
        // ---- relu^2 -> Hs (wave-local rows; in-wave lgkm ordering by compiler)
        #pragma unroll
        for (int ct = 0; ct < 2; ++ct) {
            #pragma unroll
            for (int r = 0; r < 4; ++r) {
                const int hr = w * 16 + kg * 4 + r;
                float v = fmaxf(accF[ct][r], 0.f);
                v *= v;
                const int byte = (hr * 64 + (ct * 16 + l15) * 2) ^ ((hr & 7) << 4);
                *(unsigned short*)((char*)Hs + byte) = f2bf(v);
            }
        }
        // ---- proj: 16 tok x 256 cc, K=32; lane owns cc = l15*16 + ct
        const int ar = w * 16 + l15;
        const int abyte = (ar * 64 + kg * 16) ^ ((ar & 7) << 4);
        const bf16x8 av = *(const bf16x8*)((const char*)Hs + abyte);
        #pragma unroll
        for (int ct = 0; ct < 16; ++ct) {
            const bf16x8 b = *(const bf16x8*)((const char*)bP +
                               ((ct * 64 + lane) << 4));
            accP[ct] = __builtin_amdgcn_mfma_f32_16x16x32_bf16(av, b, accP[ct], 0, 0, 0);
        }
    };

    STAGE16(fc0, fsrc);
    STAGE16(pj0, psrc);
    asm volatile("s_waitcnt vmcnt(0)" ::: "memory");
    __syncthreads();

    #pragma unroll 1
    for (int t = 0; t < NST; t += 2) {
        // phase A: prefetch t+1 -> buf1, compute buf0 (step t)
        STAGE16(fc1, fsrc + (size_t)(t + 1) * STEP_B16);
        STAGE16(pj1, psrc + (size_t)(t + 1) * STEP_B16);
        COMPUTE(fc0, pj0);
        asm volatile("s_waitcnt vmcnt(0)" ::: "memory");
        __syncthreads();
        // phase B: prefetch t+2 -> buf0, compute buf1 (step t+1)
        if (t + 2 < NST) {
            STAGE16(fc0, fsrc + (size_t)(t + 2) * STEP_B16);
            STAGE16(pj0, psrc + (size_t)(t + 2) * STEP_B16);
        }
        COMPUTE(fc1, pj1);
        asm volatile("s_waitcnt vmcnt(0)" ::: "memory");
        __syncthreads();
    }

    // ---- plain coalesced store: lane owns 16 consecutive cc (32 B)
    #pragma unroll
    for (int r = 0; r < 4; ++r) {
        const int m = tstart + w * 16 + kg * 4 + r;
        if (m < tend) {
            unsigned short* dst = Yp + (size_t)(segbase + (m - tstart) +
                                  (tstart - tstart)) * 0 +  // (kept simple below)
                                  ((size_t)(seg[e] + m) - seg[e]) * 0;
            (void)dst;
            unsigned short* d2 = Yp + (size_t)(segbase + m) * C_DIM + l15 * 16;
            bf16x8 u0, u1;
            #pragma unroll
            for (int j = 0; j < 8; ++j) {
                u0[j] = (short)f2bf(accP[j][r]);
                u1[j] = (short)f2bf(accP[j + 8][r]);
            }
            *(bf16x8*)d2       = u0;
            *(bf16x8*)(d2 + 8) = u1;
        }
    }
}

// --------------------------------------------------------------- combine ----
__global__ __launch_bounds__(256)
void combine_kernel(const unsigned short* __restrict__ Yp,
                    const int* __restrict__ seg,
                    const int* __restrict__ se, const int* __restrict__ sp,
                    const float* __restrict__ sw,
                    float* __restrict__ out)
{
    const int t = blockIdx.x * 256 + threadIdx.x;
    const int n = t >> 5;
    const int c0 = (t & 31) * 8;

    float acc[8];
    {
        const bf16x8 y = *(const bf16x8*)(Yp + (size_t)n * C_DIM + c0);
        #pragma unroll
        for (int i = 0; i < 8; ++i) acc[i] = 0.25f * bf2f((unsigned short)y[i]);
    }
    #pragma unroll
    for (int k = 0; k < 3; ++k) {
        const int e = se[n * 3 + k];
        const int row = seg[e + 1] + sp[n * 3 + k];
        const float wgt = sw[n * 3 + k];
        const bf16x8 y = *(const bf16x8*)(Yp + (size_t)row * C_DIM + c0);
        #pragma unroll
        for (int i = 0; i < 8; ++i) acc[i] = fmaf(wgt, bf2f((unsigned short)y[i]), acc[i]);
    }
    float4 o0 = make_float4(acc[0], acc[1], acc[2], acc[3]);
    float4 o1 = make_float4(acc[4], acc[5], acc[6], acc[7]);
    *(float4*)(out + (size_t)n * C_DIM + c0)     = o0;
    *(float4*)(out + (size_t)n * C_DIM + c0 + 4) = o1;
}

// ---------------------------------------------------------------- launch ----
extern "C" void kernel_launch(void* const* d_in, const int* in_sizes, int n_in,
                              void* d_out, int out_size, void* d_ws, size_t ws_size,
                              hipStream_t stream) {
    const float* x     = (const float*)d_in[0];
    const float* Wg    = (const float*)d_in[1];
    const float* Wfc   = (const float*)d_in[2];
    const float* Wpj   = (const float*)d_in[3];
    const float* ebias = (const float*)d_in[4];

    float* out = (float*)d_out;                       // [N, C]
    float* rw  = out + (size_t)N_TOK * C_DIM;         // [N, 32]

    char* ws = (char*)d_ws;
    int*   cnt  = (int*)ws;                                        ws += 256;
    int*   seg  = (int*)ws;                                        ws += 256;
    int*   toks = (int*)ws;                                        ws += (size_t)E_RT * N_TOK * 4;
    int*   se   = (int*)ws;                                        ws += (size_t)N_TOK * 3 * 4;
    int*   sp   = (int*)ws;                                        ws += (size_t)N_TOK * 3 * 4;
    float* sw   = (float*)ws;                                      ws += (size_t)N_TOK * 3 * 4;
    unsigned short* xb      = (unsigned short*)ws;                 ws += (size_t)N_TOK * C_DIM * 2;
    unsigned short* fc_img  = (unsigned short*)ws;                 ws += (size_t)E_ALL * C_DIM * H_DIM * 2;
    unsigned short* pj_img  = (unsigned short*)ws;                 ws += (size_t)E_ALL * C_DIM * H_DIM * 2;
    unsigned short* Yp      = (unsigned short*)ws;                 // ~18 MB

    zero_cnt<<<1, 64, 0, stream>>>(cnt);
    prep_x<<<(N_TOK * C_DIM / 4) / 256, 256, 0, stream>>>(x, xb);
    prep_fc<<<dim3(NSL, E_ALL), 256, 0, stream>>>(Wfc, fc_img);
    prep_pj<<<dim3(NSL, E_ALL), 256, 0, stream>>>(Wpj, pj_img);
    gate_kernel<<<N_TOK, 64, 0, stream>>>(x, Wg, ebias, rw, cnt, toks, se, sp, sw);
    finalize<<<1, 64, 0, stream>>>(cnt, seg);
    expert_kernel<<<dim3(E_ALL, N_TOK / TN), 256, 0, stream>>>(
        xb, fc_img, pj_img, cnt, seg, toks, Yp);
    combine_kernel<<<(N_TOK * 32) / 256, 256, 0, stream>>>(Yp, seg, se, sp, sw, out);
}

// Round 8
// 417.795 us; speedup vs baseline: 3.4182x; 1.2498x over previous
//
#include <hip/hip_runtime.h>
#include <hip/hip_bf16.h>
#include <cfloat>

#define N_TOK 8192
#define C_DIM 256
#define H_DIM 1024
#define E_ALL 32
#define E_RT  31
#define HS    128                     // h per image slice (prep granularity)
#define NSL   8                       // slices
#define TN    128                     // tokens per block (8 waves x 16)
#define NTILE (N_TOK / TN)            // 64
#define HC2   32                      // h per step
#define NST   (H_DIM / HC2)           // 32 steps
#define STEP_B16 16384                // bytes per weight-matrix step chunk
#define SLICE_B (HS * C_DIM * 2)      // 64 KB per slice

typedef __attribute__((ext_vector_type(8))) short bf16x8;
typedef __attribute__((ext_vector_type(4))) float f32x4;

__device__ __forceinline__ unsigned short f2bf(float f) {
    return __builtin_bit_cast(unsigned short, __float2bfloat16(f));
}
__device__ __forceinline__ float bf2f(unsigned short u) {
    unsigned int x = ((unsigned int)u) << 16;
    return __builtin_bit_cast(float, x);
}
__device__ __forceinline__ void gld16(void* lds, const void* g) {
    __builtin_amdgcn_global_load_lds(
        (const __attribute__((address_space(1))) void*)g,
        (__attribute__((address_space(3))) void*)lds, 16, 0, 0);
}

// ---------------------------------------------------------------- gating ----
__global__ __launch_bounds__(64)
void gate_kernel(const float* __restrict__ x, const float* __restrict__ Wg,
                 const float* __restrict__ ebias,
                 float* __restrict__ rw, int* __restrict__ cnt,
                 int* __restrict__ toks,
                 int* __restrict__ se, int* __restrict__ sp, float* __restrict__ sw)
{
    const int n = blockIdx.x;
    const int lane = threadIdx.x;

    __shared__ float xs[C_DIM];
    ((float4*)xs)[lane] = ((const float4*)(x + (size_t)n * C_DIM))[lane];
    __syncthreads();

    float logit = -FLT_MAX;
    if (lane < E_RT) {
        float s = 0.f;
        #pragma unroll 4
        for (int c = 0; c < C_DIM; ++c)
            s = fmaf(xs[c], Wg[c * E_RT + lane], s);
        logit = s;
    }

    float m = logit;
    for (int off = 32; off; off >>= 1) m = fmaxf(m, __shfl_xor(m, off));
    float ev = (lane < E_RT) ? expf(logit - m) : 0.f;
    float sum = ev;
    for (int off = 32; off; off >>= 1) sum += __shfl_xor(sum, off);
    float gate = ev / sum;
    float biased = (lane < E_RT) ? gate + ebias[lane] : -FLT_MAX;

    float val[3]; int idx[3];
    float cur = biased;
    #pragma unroll
    for (int k = 0; k < 3; ++k) {
        float mk = cur;
        for (int off = 32; off; off >>= 1) mk = fmaxf(mk, __shfl_xor(mk, off));
        unsigned long long ball = __ballot(cur == mk && lane < E_RT);
        int sel = __ffsll(ball) - 1;
        val[k] = mk; idx[k] = sel;
        if (lane == sel) cur = -FLT_MAX;
    }

    float st = val[0] + val[1] + val[2];
    float wr0 = val[0] / st * 0.75f;
    float wr1 = val[1] / st * 0.75f;
    float wr2 = val[2] / st * 0.75f;

    if (lane < E_ALL) {
        float v = 0.f;
        if (lane == 0)          v = 0.25f;
        if (lane == idx[0] + 1) v = wr0;
        if (lane == idx[1] + 1) v = wr1;
        if (lane == idx[2] + 1) v = wr2;
        rw[(size_t)n * E_ALL + lane] = v;
    }

    if (lane == 0) {
        float wv[3] = {wr0, wr1, wr2};
        #pragma unroll
        for (int k = 0; k < 3; ++k) {
            int e31 = idx[k];
            int pos = atomicAdd(&cnt[e31], 1);
            toks[e31 * N_TOK + pos] = n;
            se[n * 3 + k] = e31;
            sp[n * 3 + k] = pos;
            sw[n * 3 + k] = wv[k];
        }
    }
}

__global__ void zero_cnt(int* cnt) { if (threadIdx.x < E_RT) cnt[threadIdx.x] = 0; }

// seg[0]=0 (shared rows); seg[e31+1]=rowbase of routed expert e31, 64-padded
__global__ void finalize(const int* __restrict__ cnt, int* __restrict__ seg) {
    if (threadIdx.x == 0) {
        int b = N_TOK;
        seg[0] = 0;
        for (int i = 0; i < E_RT; ++i) { seg[i + 1] = b; b += (cnt[i] + 63) & ~63; }
    }
}

// -------------------------------------------------------------- x -> bf16 ---
__global__ __launch_bounds__(256)
void prep_x(const float* __restrict__ x, unsigned short* __restrict__ xb)
{
    const int t = blockIdx.x * 256 + threadIdx.x;
    const float4 v = ((const float4*)x)[t];
    ushort4 b;
    b.x = f2bf(v.x); b.y = f2bf(v.y); b.z = f2bf(v.z); b.w = f2bf(v.w);
    ((ushort4*)xb)[t] = b;
}

// -------------------------------------- weight prep: MFMA-fragment images ---
// fc image per (e,s): 64 lines, CT-MAJOR (li = ct*8 + ks); line = 64 lanes x 16B:
//   value(lane=(l15,kg), j) = Wfc[e][c = ks*32+kg*8+j][h = s*128 + ct*16 + l15]
__global__ __launch_bounds__(256)
void prep_fc(const float* __restrict__ Wfc, unsigned short* __restrict__ img)
{
    const int s = blockIdx.x, e = blockIdx.y;
    const int h0 = s * HS;
    __shared__ unsigned short tb[C_DIM * HS];     // [c][hh] bf16, 64 KB
    const int tid = threadIdx.x;
    #pragma unroll
    for (int i = 0; i < 32; ++i) {
        const int fidx = i * 1024 + tid * 4;
        const int c = fidx >> 7, hh = fidx & 127;
        const float4 v = *(const float4*)(Wfc + ((size_t)e * C_DIM + c) * H_DIM + h0 + hh);
        ushort4 b;
        b.x = f2bf(v.x); b.y = f2bf(v.y); b.z = f2bf(v.z); b.w = f2bf(v.w);
        *(ushort4*)(tb + c * HS + hh) = b;
    }
    __syncthreads();
    const int lane = tid & 63, w = tid >> 6;
    const int l15 = lane & 15, kg = lane >> 4;
    unsigned short* dst = img + ((size_t)e * NSL + s) * (SLICE_B / 2);
    for (int li = w; li < 64; li += 4) {
        const int ct = li >> 3, ks = li & 7;      // ct-major
        bf16x8 v;
        #pragma unroll
        for (int j = 0; j < 8; ++j)
            v[j] = (short)tb[(ks * 32 + kg * 8 + j) * HS + ct * 16 + l15];
        *(bf16x8*)(dst + (size_t)li * 512 + lane * 8) = v;
    }
}

// pj image per (e,s): 64 lines, KS-MAJOR (li = ks*16 + ct):
//   value(lane, j) = Wpj[e][h = s*128 + ks*32 + kg*8 + j][cc = ct + l15*16]
__global__ __launch_bounds__(256)
void prep_pj(const float* __restrict__ Wpj, unsigned short* __restrict__ img)
{
    const int s = blockIdx.x, e = blockIdx.y;
    const int h0 = s * HS;
    __shared__ unsigned short tb[HS * C_DIM];     // [r(h)][cc] bf16, 64 KB
    const int tid = threadIdx.x;
    #pragma unroll
    for (int i = 0; i < 32; ++i) {
        const int fidx = i * 1024 + tid * 4;
        const int r = fidx >> 8, cc = fidx & 255;
        const float4 v = *(const float4*)(Wpj + ((size_t)e * H_DIM + h0 + r) * C_DIM + cc);
        ushort4 b;
        b.x = f2bf(v.x); b.y = f2bf(v.y); b.z = f2bf(v.z); b.w = f2bf(v.w);
        *(ushort4*)(tb + r * C_DIM + cc) = b;
    }
    __syncthreads();
    const int lane = tid & 63, w = tid >> 6;
    const int l15 = lane & 15, kg = lane >> 4;
    unsigned short* dst = img + ((size_t)e * NSL + s) * (SLICE_B / 2);
    for (int li = w; li < 64; li += 4) {
        const int ks = li >> 4, ct = li & 15;
        bf16x8 v;
        #pragma unroll
        for (int j = 0; j < 8; ++j)
            v[j] = (short)tb[(ks * 32 + kg * 8 + j) * C_DIM + ct + l15 * 16];
        *(bf16x8*)(dst + (size_t)li * 512 + lane * 8) = v;
    }
}

// --------------------------------------------------------------- experts ----
__global__ __launch_bounds__(512)
void expert_kernel(const unsigned short* __restrict__ xb,
                   const unsigned short* __restrict__ fc_img,
                   const unsigned short* __restrict__ pj_img,
                   const int* __restrict__ cnt,
                   const int* __restrict__ seg,
                   const int* __restrict__ toks,
                   unsigned short* __restrict__ Yp)
{
    const int e = blockIdx.y;                    // tile index is x (fastest):
    const int tstart = blockIdx.x * TN;          // active blocks contiguous in
    const int count = (e == 0) ? N_TOK : cnt[e - 1];   // dispatch order
    if (tstart >= count) return;
    const int tend = min(tstart + TN, count);
    const int segbase = seg[e];

    // static double buffers (distinct objects -> no alias-forced drains)
    __shared__ unsigned short fc0[STEP_B16 / 2];
    __shared__ unsigned short fc1[STEP_B16 / 2];
    __shared__ unsigned short pj0[STEP_B16 / 2];
    __shared__ unsigned short pj1[STEP_B16 / 2];
    __shared__ unsigned short Hs[TN * HC2];       // 8 KB, wave-local rows

    const int tid  = threadIdx.x;
    const int lane = tid & 63;
    const int w    = tid >> 6;                    // 0..7
    const int l15  = lane & 15;
    const int kg   = lane >> 4;

    // my token (A-row = w*16 + l15)
    const int p = tstart + w * 16 + l15;
    int tok = 0;
    if (p < tend) tok = (e == 0) ? p : toks[(e - 1) * N_TOK + p];

    // A fragments in registers for all steps
    bf16x8 aF[8];
    const unsigned short* xr = xb + (size_t)tok * C_DIM + kg * 8;
    #pragma unroll
    for (int ks = 0; ks < 8; ++ks)
        aF[ks] = *(const bf16x8*)(xr + ks * 32);

    f32x4 accP[16];
    #pragma unroll
    for (int i = 0; i < 16; ++i) accP[i] = (f32x4){0.f, 0.f, 0.f, 0.f};

    const char* fsrc = (const char*)fc_img + (size_t)e * NSL * SLICE_B;
    const char* psrc = (const char*)pj_img + (size_t)e * NSL * SLICE_B;

    auto STAGE16 = [&](unsigned short* dst, const char* src) {  // 16 KB linear
        #pragma unroll
        for (int i = 0; i < 2; ++i) {             // 512 thr x 16B x 2
            const int off = i * 8192 + tid * 16;
            gld16((char*)dst + off, src + off);
        }
    };

    auto COMPUTE = [&](const unsigned short* bF, const unsigned short* bP) {
        // ---- fc: 16 tok x 32 h, K=256; B reads conflict-free
        f32x4 accF[2];
        accF[0] = (f32x4){0.f, 0.f, 0.f, 0.f};
        accF[1] = (f32x4){0.f, 0.f, 0.f, 0.f};
        #pragma unroll
        for (int ks = 0; ks < 8; ++ks) {
            #pragma unroll
            for (int ct = 0; ct < 2; ++ct) {
                const bf16x8 b = *(const bf16x8*)((const char*)bF +
                                   (((ct * 8 + ks) * 64 + lane) << 4));
                accF[ct] = __builtin_amdgcn_mfma_f32_16x16x32_bf16(aF[ks], b, accF[ct], 0, 0, 0);
            }
        }
        // ---- relu^2 -> Hs (wave-local rows)
        #pragma unroll
        for (int ct = 0; ct < 2; ++ct) {
            #pragma unroll
            for (int r = 0; r < 4; ++r) {
                const int hr = w * 16 + kg * 4 + r;
                float v = fmaxf(accF[ct][r], 0.f);
                v *= v;
                const int byte = (hr * 64 + (ct * 16 + l15) * 2) ^ ((hr & 7) << 4);
                *(unsigned short*)((char*)Hs + byte) = f2bf(v);
            }
        }
        // ---- proj: 16 tok x 256 cc, K=32; lane owns cc = l15*16 + ct
        const int ar = w * 16 + l15;
        const int abyte = (ar * 64 + kg * 16) ^ ((ar & 7) << 4);
        const bf16x8 av = *(const bf16x8*)((const char*)Hs + abyte);
        #pragma unroll
        for (int ct = 0; ct < 16; ++ct) {
            const bf16x8 b = *(const bf16x8*)((const char*)bP +
                               ((ct * 64 + lane) << 4));
            accP[ct] = __builtin_amdgcn_mfma_f32_16x16x32_bf16(av, b, accP[ct], 0, 0, 0);
        }
    };

    // prologue: stage step 0, fence so aF/step-0 loads stay oldest
    STAGE16(fc0, fsrc);
    STAGE16(pj0, psrc);
    asm volatile("" ::: "memory");

    #pragma unroll 1
    for (int t = 0; t < NST - 1; ++t) {
        // issue next step's stage (4 VMEM instrs/wave), then counted wait:
        // leave exactly those 4 in flight across compute + both barriers
        if (t & 1) { STAGE16(fc0, fsrc + (size_t)(t + 1) * STEP_B16);
                     STAGE16(pj0, psrc + (size_t)(t + 1) * STEP_B16); }
        else       { STAGE16(fc1, fsrc + (size_t)(t + 1) * STEP_B16);
                     STAGE16(pj1, psrc + (size_t)(t + 1) * STEP_B16); }
        asm volatile("s_waitcnt vmcnt(4)" ::: "memory");   // cur step landed
        __builtin_amdgcn_s_barrier();                       // visible to all
        if (t & 1) COMPUTE(fc1, pj1);
        else       COMPUTE(fc0, pj0);
        __builtin_amdgcn_s_barrier();                       // WAR before overwrite
    }
    // last step (NST-1 is odd -> buffers fc1/pj1)
    asm volatile("s_waitcnt vmcnt(0)" ::: "memory");
    __builtin_amdgcn_s_barrier();
    COMPUTE(fc1, pj1);

    // ---- plain coalesced store: lane owns 16 consecutive cc (32 B)
    #pragma unroll
    for (int r = 0; r < 4; ++r) {
        const int m = tstart + w * 16 + kg * 4 + r;
        if (m < tend) {
            unsigned short* d2 = Yp + (size_t)(segbase + m) * C_DIM + l15 * 16;
            bf16x8 u0, u1;
            #pragma unroll
            for (int j = 0; j < 8; ++j) {
                u0[j] = (short)f2bf(accP[j][r]);
                u1[j] = (short)f2bf(accP[j + 8][r]);
            }
            *(bf16x8*)d2       = u0;
            *(bf16x8*)(d2 + 8) = u1;
        }
    }
}

// --------------------------------------------------------------- combine ----
__global__ __launch_bounds__(256)
void combine_kernel(const unsigned short* __restrict__ Yp,
                    const int* __restrict__ seg,
                    const int* __restrict__ se, const int* __restrict__ sp,
                    const float* __restrict__ sw,
                    float* __restrict__ out)
{
    const int t = blockIdx.x * 256 + threadIdx.x;
    const int n = t >> 5;
    const int c0 = (t & 31) * 8;

    float acc[8];
    {
        const bf16x8 y = *(const bf16x8*)(Yp + (size_t)n * C_DIM + c0);
        #pragma unroll
        for (int i = 0; i < 8; ++i) acc[i] = 0.25f * bf2f((unsigned short)y[i]);
    }
    #pragma unroll
    for (int k = 0; k < 3; ++k) {
        const int e = se[n * 3 + k];
        const int row = seg[e + 1] + sp[n * 3 + k];
        const float wgt = sw[n * 3 + k];
        const bf16x8 y = *(const bf16x8*)(Yp + (size_t)row * C_DIM + c0);
        #pragma unroll
        for (int i = 0; i < 8; ++i) acc[i] = fmaf(wgt, bf2f((unsigned short)y[i]), acc[i]);
    }
    float4 o0 = make_float4(acc[0], acc[1], acc[2], acc[3]);
    float4 o1 = make_float4(acc[4], acc[5], acc[6], acc[7]);
    *(float4*)(out + (size_t)n * C_DIM + c0)     = o0;
    *(float4*)(out + (size_t)n * C_DIM + c0 + 4) = o1;
}

// ---------------------------------------------------------------- launch ----
extern "C" void kernel_launch(void* const* d_in, const int* in_sizes, int n_in,
                              void* d_out, int out_size, void* d_ws, size_t ws_size,
                              hipStream_t stream) {
    const float* x     = (const float*)d_in[0];
    const float* Wg    = (const float*)d_in[1];
    const float* Wfc   = (const float*)d_in[2];
    const float* Wpj   = (const float*)d_in[3];
    const float* ebias = (const float*)d_in[4];

    float* out = (float*)d_out;                       // [N, C]
    float* rw  = out + (size_t)N_TOK * C_DIM;         // [N, 32]

    char* ws = (char*)d_ws;
    int*   cnt  = (int*)ws;                                        ws += 256;
    int*   seg  = (int*)ws;                                        ws += 256;
    int*   toks = (int*)ws;                                        ws += (size_t)E_RT * N_TOK * 4;
    int*   se   = (int*)ws;                                        ws += (size_t)N_TOK * 3 * 4;
    int*   sp   = (int*)ws;                                        ws += (size_t)N_TOK * 3 * 4;
    float* sw   = (float*)ws;                                      ws += (size_t)N_TOK * 3 * 4;
    unsigned short* xb      = (unsigned short*)ws;                 ws += (size_t)N_TOK * C_DIM * 2;
    unsigned short* fc_img  = (unsigned short*)ws;                 ws += (size_t)E_ALL * C_DIM * H_DIM * 2;
    unsigned short* pj_img  = (unsigned short*)ws;                 ws += (size_t)E_ALL * C_DIM * H_DIM * 2;
    unsigned short* Yp      = (unsigned short*)ws;                 // ~18 MB

    zero_cnt<<<1, 64, 0, stream>>>(cnt);
    prep_x<<<(N_TOK * C_DIM / 4) / 256, 256, 0, stream>>>(x, xb);
    prep_fc<<<dim3(NSL, E_ALL), 256, 0, stream>>>(Wfc, fc_img);
    prep_pj<<<dim3(NSL, E_ALL), 256, 0, stream>>>(Wpj, pj_img);
    gate_kernel<<<N_TOK, 64, 0, stream>>>(x, Wg, ebias, rw, cnt, toks, se, sp, sw);
    finalize<<<1, 64, 0, stream>>>(cnt, seg);
    expert_kernel<<<dim3(NTILE, E_ALL), 512, 0, stream>>>(
        xb, fc_img, pj_img, cnt, seg, toks, Yp);
    combine_kernel<<<(N_TOK * 32) / 256, 256, 0, stream>>>(Yp, seg, se, sp, sw, out);
}

// Round 9
// 314.329 us; speedup vs baseline: 4.5433x; 1.3292x over previous
//
#include <hip/hip_runtime.h>
#include <hip/hip_bf16.h>
#include <cfloat>

#define N_TOK 8192
#define C_DIM 256
#define H_DIM 1024
#define E_ALL 32
#define E_RT  31
#define HS    128                     // h per image slice (prep granularity)
#define NSL   8                       // slices
#define TN    128                     // tokens per block (4 waves x 32)
#define HC2   32                      // h per step
#define NST   (H_DIM / HC2)           // 32 steps
#define STEP_B16 16384                // bytes per weight-matrix step chunk
#define SLICE_B (HS * C_DIM * 2)      // 64 KB per slice
#define MAXBLK 287                    // 64 (e0) + 192 + 31 (routed ceil bound)

typedef __attribute__((ext_vector_type(8))) short bf16x8;
typedef __attribute__((ext_vector_type(4))) float f32x4;

__device__ __forceinline__ unsigned short f2bf(float f) {
    return __builtin_bit_cast(unsigned short, __float2bfloat16(f));
}
__device__ __forceinline__ float bf2f(unsigned short u) {
    unsigned int x = ((unsigned int)u) << 16;
    return __builtin_bit_cast(float, x);
}
__device__ __forceinline__ void gld16(void* lds, const void* g) {
    __builtin_amdgcn_global_load_lds(
        (const __attribute__((address_space(1))) void*)g,
        (__attribute__((address_space(3))) void*)lds, 16, 0, 0);
}

// ------------------------------------------------- gating (+ x->bf16 fold) --
__global__ __launch_bounds__(64)
void gate_kernel(const float* __restrict__ x, const float* __restrict__ Wg,
                 const float* __restrict__ ebias,
                 float* __restrict__ rw, int* __restrict__ cnt,
                 int* __restrict__ toks,
                 int* __restrict__ se, int* __restrict__ sp, float* __restrict__ sw,
                 unsigned short* __restrict__ xb)
{
    const int n = blockIdx.x;
    const int lane = threadIdx.x;

    __shared__ float xs[C_DIM];
    const float4 xv = ((const float4*)(x + (size_t)n * C_DIM))[lane];
    ((float4*)xs)[lane] = xv;
    {   // folded prep_x: write bf16 row
        ushort4 b;
        b.x = f2bf(xv.x); b.y = f2bf(xv.y); b.z = f2bf(xv.z); b.w = f2bf(xv.w);
        ((ushort4*)(xb + (size_t)n * C_DIM))[lane] = b;
    }
    __syncthreads();

    float logit = -FLT_MAX;
    if (lane < E_RT) {
        float s = 0.f;
        #pragma unroll 4
        for (int c = 0; c < C_DIM; ++c)
            s = fmaf(xs[c], Wg[c * E_RT + lane], s);
        logit = s;
    }

    float m = logit;
    for (int off = 32; off; off >>= 1) m = fmaxf(m, __shfl_xor(m, off));
    float ev = (lane < E_RT) ? expf(logit - m) : 0.f;
    float sum = ev;
    for (int off = 32; off; off >>= 1) sum += __shfl_xor(sum, off);
    float gate = ev / sum;
    float biased = (lane < E_RT) ? gate + ebias[lane] : -FLT_MAX;

    float val[3]; int idx[3];
    float cur = biased;
    #pragma unroll
    for (int k = 0; k < 3; ++k) {
        float mk = cur;
        for (int off = 32; off; off >>= 1) mk = fmaxf(mk, __shfl_xor(mk, off));
        unsigned long long ball = __ballot(cur == mk && lane < E_RT);
        int sel = __ffsll(ball) - 1;
        val[k] = mk; idx[k] = sel;
        if (lane == sel) cur = -FLT_MAX;
    }

    float st = val[0] + val[1] + val[2];
    float wr0 = val[0] / st * 0.75f;
    float wr1 = val[1] / st * 0.75f;
    float wr2 = val[2] / st * 0.75f;

    if (lane < E_ALL) {
        float v = 0.f;
        if (lane == 0)          v = 0.25f;
        if (lane == idx[0] + 1) v = wr0;
        if (lane == idx[1] + 1) v = wr1;
        if (lane == idx[2] + 1) v = wr2;
        rw[(size_t)n * E_ALL + lane] = v;
    }

    if (lane == 0) {
        float wv[3] = {wr0, wr1, wr2};
        #pragma unroll
        for (int k = 0; k < 3; ++k) {
            int e31 = idx[k];
            int pos = atomicAdd(&cnt[e31], 1);
            toks[e31 * N_TOK + pos] = n;
            se[n * 3 + k] = e31;
            sp[n * 3 + k] = pos;
            sw[n * 3 + k] = wv[k];
        }
    }
}

// seg + dense active-block map (contiguous dispatch -> even CU spread)
__global__ void finalize(const int* __restrict__ cnt, int* __restrict__ seg,
                         unsigned int* __restrict__ map) {
    if (threadIdx.x == 0) {
        int blk = 0;
        for (int t = 0; t < N_TOK / TN; ++t) map[blk++] = (unsigned)t;   // e = 0
        int b = N_TOK;
        seg[0] = 0;
        for (int i = 0; i < E_RT; ++i) {
            seg[i + 1] = b; b += (cnt[i] + 63) & ~63;
            const int nt = (cnt[i] + TN - 1) / TN;
            for (int t = 0; t < nt; ++t)
                map[blk++] = ((unsigned)(i + 1) << 8) | (unsigned)t;
        }
        for (; blk < MAXBLK; ++blk) map[blk] = 0xFFFFFFFFu;
    }
}

// -------------------------------------- weight prep: MFMA-fragment images ---
__global__ __launch_bounds__(256)
void prep_fc(const float* __restrict__ Wfc, unsigned short* __restrict__ img)
{
    const int s = blockIdx.x, e = blockIdx.y;
    const int h0 = s * HS;
    __shared__ unsigned short tb[C_DIM * HS];     // [c][hh] bf16, 64 KB
    const int tid = threadIdx.x;
    #pragma unroll
    for (int i = 0; i < 32; ++i) {
        const int fidx = i * 1024 + tid * 4;
        const int c = fidx >> 7, hh = fidx & 127;
        const float4 v = *(const float4*)(Wfc + ((size_t)e * C_DIM + c) * H_DIM + h0 + hh);
        ushort4 b;
        b.x = f2bf(v.x); b.y = f2bf(v.y); b.z = f2bf(v.z); b.w = f2bf(v.w);
        *(ushort4*)(tb + c * HS + hh) = b;
    }
    __syncthreads();
    const int lane = tid & 63, w = tid >> 6;
    const int l15 = lane & 15, kg = lane >> 4;
    unsigned short* dst = img + ((size_t)e * NSL + s) * (SLICE_B / 2);
    for (int li = w; li < 64; li += 4) {
        const int ct = li >> 3, ks = li & 7;      // ct-major
        bf16x8 v;
        #pragma unroll
        for (int j = 0; j < 8; ++j)
            v[j] = (short)tb[(ks * 32 + kg * 8 + j) * HS + ct * 16 + l15];
        *(bf16x8*)(dst + (size_t)li * 512 + lane * 8) = v;
    }
}

__global__ __launch_bounds__(256)
void prep_pj(const float* __restrict__ Wpj, unsigned short* __restrict__ img)
{
    const int s = blockIdx.x, e = blockIdx.y;
    const int h0 = s * HS;
    __shared__ unsigned short tb[HS * C_DIM];     // [r(h)][cc] bf16, 64 KB
    const int tid = threadIdx.x;
    #pragma unroll
    for (int i = 0; i < 32; ++i) {
        const int fidx = i * 1024 + tid * 4;
        const int r = fidx >> 8, cc = fidx & 255;
        const float4 v = *(const float4*)(Wpj + ((size_t)e * H_DIM + h0 + r) * C_DIM + cc);
        ushort4 b;
        b.x = f2bf(v.x); b.y = f2bf(v.y); b.z = f2bf(v.z); b.w = f2bf(v.w);
        *(ushort4*)(tb + r * C_DIM + cc) = b;
    }
    __syncthreads();
    const int lane = tid & 63, w = tid >> 6;
    const int l15 = lane & 15, kg = lane >> 4;
    unsigned short* dst = img + ((size_t)e * NSL + s) * (SLICE_B / 2);
    for (int li = w; li < 64; li += 4) {
        const int ks = li >> 4, ct = li & 15;
        bf16x8 v;
        #pragma unroll
        for (int j = 0; j < 8; ++j)
            v[j] = (short)tb[(ks * 32 + kg * 8 + j) * C_DIM + ct + l15 * 16];
        *(bf16x8*)(dst + (size_t)li * 512 + lane * 8) = v;
    }
}

// ----------------------------- experts: dense map, 4 waves, 32 tokens/wave --
__global__ __launch_bounds__(256)
void expert_kernel(const unsigned short* __restrict__ xb,
                   const unsigned short* __restrict__ fc_img,
                   const unsigned short* __restrict__ pj_img,
                   const int* __restrict__ cnt,
                   const int* __restrict__ seg,
                   const int* __restrict__ toks,
                   const unsigned int* __restrict__ map,
                   unsigned short* __restrict__ Yp)
{
    const unsigned int mp = map[blockIdx.x];
    if (mp == 0xFFFFFFFFu) return;
    const int e = mp >> 8;
    const int tstart = (int)(mp & 255u) * TN;
    const int count = (e == 0) ? N_TOK : cnt[e - 1];
    const int tend = min(tstart + TN, count);
    const int segbase = seg[e];

    __shared__ unsigned short fc0[STEP_B16 / 2];
    __shared__ unsigned short fc1[STEP_B16 / 2];
    __shared__ unsigned short pj0[STEP_B16 / 2];
    __shared__ unsigned short pj1[STEP_B16 / 2];
    __shared__ unsigned short Hs[TN * HC2];       // 8 KB, wave-local rows

    const int tid  = threadIdx.x;
    const int lane = tid & 63;
    const int w    = tid >> 6;                    // 0..3, owns rows w*32..+31
    const int l15  = lane & 15;
    const int kg   = lane >> 4;

    // two token rows per thread-slot (mg = 0,1)
    int tok0 = 0, tok1 = 0;
    {
        const int p0 = tstart + w * 32 + l15;
        const int p1 = p0 + 16;
        if (p0 < tend) tok0 = (e == 0) ? p0 : toks[(e - 1) * N_TOK + p0];
        if (p1 < tend) tok1 = (e == 0) ? p1 : toks[(e - 1) * N_TOK + p1];
    }

    bf16x8 aF0[8], aF1[8];
    {
        const unsigned short* xr0 = xb + (size_t)tok0 * C_DIM + kg * 8;
        const unsigned short* xr1 = xb + (size_t)tok1 * C_DIM + kg * 8;
        #pragma unroll
        for (int ks = 0; ks < 8; ++ks) {
            aF0[ks] = *(const bf16x8*)(xr0 + ks * 32);
            aF1[ks] = *(const bf16x8*)(xr1 + ks * 32);
        }
    }

    f32x4 accP0[16], accP1[16];
    #pragma unroll
    for (int i = 0; i < 16; ++i) {
        accP0[i] = (f32x4){0.f, 0.f, 0.f, 0.f};
        accP1[i] = (f32x4){0.f, 0.f, 0.f, 0.f};
    }

    const char* fsrc = (const char*)fc_img + (size_t)e * NSL * SLICE_B;
    const char* psrc = (const char*)pj_img + (size_t)e * NSL * SLICE_B;

    auto STAGE16 = [&](unsigned short* dst, const char* src) {  // 16 KB linear
        #pragma unroll
        for (int i = 0; i < 4; ++i) {             // 256 thr x 16B x 4
            const int off = i * 4096 + tid * 16;
            gld16((char*)dst + off, src + off);
        }
    };

    auto COMPUTE = [&](const unsigned short* bF, const unsigned short* bP) {
        // ---- fc: 32 tok x 32 h, K=256; each B-frag read feeds 2 MFMAs
        f32x4 accFa[2], accFb[2];
        accFa[0] = (f32x4){0.f, 0.f, 0.f, 0.f};
        accFa[1] = (f32x4){0.f, 0.f, 0.f, 0.f};
        accFb[0] = (f32x4){0.f, 0.f, 0.f, 0.f};
        accFb[1] = (f32x4){0.f, 0.f, 0.f, 0.f};
        #pragma unroll
        for (int ks = 0; ks < 8; ++ks) {
            #pragma unroll
            for (int ct = 0; ct < 2; ++ct) {
                const bf16x8 b = *(const bf16x8*)((const char*)bF +
                                   (((ct * 8 + ks) * 64 + lane) << 4));
                accFa[ct] = __builtin_amdgcn_mfma_f32_16x16x32_bf16(aF0[ks], b, accFa[ct], 0, 0, 0);
                accFb[ct] = __builtin_amdgcn_mfma_f32_16x16x32_bf16(aF1[ks], b, accFb[ct], 0, 0, 0);
            }
        }
        // ---- relu^2 -> Hs (wave-local rows)
        #pragma unroll
        for (int ct = 0; ct < 2; ++ct) {
            #pragma unroll
            for (int r = 0; r < 4; ++r) {
                {
                    const int hr = w * 32 + kg * 4 + r;
                    float v = fmaxf(accFa[ct][r], 0.f); v *= v;
                    const int byte = (hr * 64 + (ct * 16 + l15) * 2) ^ ((hr & 7) << 4);
                    *(unsigned short*)((char*)Hs + byte) = f2bf(v);
                }
                {
                    const int hr = w * 32 + 16 + kg * 4 + r;
                    float v = fmaxf(accFb[ct][r], 0.f); v *= v;
                    const int byte = (hr * 64 + (ct * 16 + l15) * 2) ^ ((hr & 7) << 4);
                    *(unsigned short*)((char*)Hs + byte) = f2bf(v);
                }
            }
        }
        // ---- proj: 32 tok x 256 cc, K=32; lane owns cc = l15*16 + ct
        const int ar0 = w * 32 + l15;
        const int ar1 = ar0 + 16;
        const int ab0 = (ar0 * 64 + kg * 16) ^ ((ar0 & 7) << 4);
        const int ab1 = (ar1 * 64 + kg * 16) ^ ((ar1 & 7) << 4);
        const bf16x8 av0 = *(const bf16x8*)((const char*)Hs + ab0);
        const bf16x8 av1 = *(const bf16x8*)((const char*)Hs + ab1);
        #pragma unroll
        for (int ct = 0; ct < 16; ++ct) {
            const bf16x8 b = *(const bf16x8*)((const char*)bP +
                               ((ct * 64 + lane) << 4));
            accP0[ct] = __builtin_amdgcn_mfma_f32_16x16x32_bf16(av0, b, accP0[ct], 0, 0, 0);
            accP1[ct] = __builtin_amdgcn_mfma_f32_16x16x32_bf16(av1, b, accP1[ct], 0, 0, 0);
        }
    };

    STAGE16(fc0, fsrc);
    STAGE16(pj0, psrc);
    asm volatile("" ::: "memory");

    #pragma unroll 1
    for (int t = 0; t < NST - 1; ++t) {
        if (t & 1) { STAGE16(fc0, fsrc + (size_t)(t + 1) * STEP_B16);
                     STAGE16(pj0, psrc + (size_t)(t + 1) * STEP_B16); }
        else       { STAGE16(fc1, fsrc + (size_t)(t + 1) * STEP_B16);
                     STAGE16(pj1, psrc + (size_t)(t + 1) * STEP_B16); }
        asm volatile("s_waitcnt vmcnt(8)" ::: "memory");   // cur step landed
        __builtin_amdgcn_s_barrier();
        if (t & 1) COMPUTE(fc1, pj1);
        else       COMPUTE(fc0, pj0);
        __builtin_amdgcn_s_barrier();                       // WAR before overwrite
    }
    asm volatile("s_waitcnt vmcnt(0)" ::: "memory");
    __builtin_amdgcn_s_barrier();
    COMPUTE(fc1, pj1);                                      // NST-1 odd -> buf1

    // ---- plain coalesced stores: lane owns 16 consecutive cc (32 B)
    #pragma unroll
    for (int r = 0; r < 4; ++r) {
        const int m0 = tstart + w * 32 + kg * 4 + r;
        if (m0 < tend) {
            unsigned short* d2 = Yp + (size_t)(segbase + m0) * C_DIM + l15 * 16;
            bf16x8 u0, u1;
            #pragma unroll
            for (int j = 0; j < 8; ++j) {
                u0[j] = (short)f2bf(accP0[j][r]);
                u1[j] = (short)f2bf(accP0[j + 8][r]);
            }
            *(bf16x8*)d2       = u0;
            *(bf16x8*)(d2 + 8) = u1;
        }
        const int m1 = tstart + w * 32 + 16 + kg * 4 + r;
        if (m1 < tend) {
            unsigned short* d2 = Yp + (size_t)(segbase + m1) * C_DIM + l15 * 16;
            bf16x8 u0, u1;
            #pragma unroll
            for (int j = 0; j < 8; ++j) {
                u0[j] = (short)f2bf(accP1[j][r]);
                u1[j] = (short)f2bf(accP1[j + 8][r]);
            }
            *(bf16x8*)d2       = u0;
            *(bf16x8*)(d2 + 8) = u1;
        }
    }
}

// --------------------------------------------------------------- combine ----
__global__ __launch_bounds__(256)
void combine_kernel(const unsigned short* __restrict__ Yp,
                    const int* __restrict__ seg,
                    const int* __restrict__ se, const int* __restrict__ sp,
                    const float* __restrict__ sw,
                    float* __restrict__ out)
{
    const int t = blockIdx.x * 256 + threadIdx.x;
    const int n = t >> 5;
    const int c0 = (t & 31) * 8;

    float acc[8];
    {
        const bf16x8 y = *(const bf16x8*)(Yp + (size_t)n * C_DIM + c0);
        #pragma unroll
        for (int i = 0; i < 8; ++i) acc[i] = 0.25f * bf2f((unsigned short)y[i]);
    }
    #pragma unroll
    for (int k = 0; k < 3; ++k) {
        const int e = se[n * 3 + k];
        const int row = seg[e + 1] + sp[n * 3 + k];
        const float wgt = sw[n * 3 + k];
        const bf16x8 y = *(const bf16x8*)(Yp + (size_t)row * C_DIM + c0);
        #pragma unroll
        for (int i = 0; i < 8; ++i) acc[i] = fmaf(wgt, bf2f((unsigned short)y[i]), acc[i]);
    }
    float4 o0 = make_float4(acc[0], acc[1], acc[2], acc[3]);
    float4 o1 = make_float4(acc[4], acc[5], acc[6], acc[7]);
    *(float4*)(out + (size_t)n * C_DIM + c0)     = o0;
    *(float4*)(out + (size_t)n * C_DIM + c0 + 4) = o1;
}

// ---------------------------------------------------------------- launch ----
extern "C" void kernel_launch(void* const* d_in, const int* in_sizes, int n_in,
                              void* d_out, int out_size, void* d_ws, size_t ws_size,
                              hipStream_t stream) {
    const float* x     = (const float*)d_in[0];
    const float* Wg    = (const float*)d_in[1];
    const float* Wfc   = (const float*)d_in[2];
    const float* Wpj   = (const float*)d_in[3];
    const float* ebias = (const float*)d_in[4];

    float* out = (float*)d_out;                       // [N, C]
    float* rw  = out + (size_t)N_TOK * C_DIM;         // [N, 32]

    char* ws = (char*)d_ws;
    int*          cnt  = (int*)ws;                                 ws += 256;
    int*          seg  = (int*)ws;                                 ws += 256;
    unsigned int* map  = (unsigned int*)ws;                        ws += 2048;
    int*   toks = (int*)ws;                                        ws += (size_t)E_RT * N_TOK * 4;
    int*   se   = (int*)ws;                                        ws += (size_t)N_TOK * 3 * 4;
    int*   sp   = (int*)ws;                                        ws += (size_t)N_TOK * 3 * 4;
    float* sw   = (float*)ws;                                      ws += (size_t)N_TOK * 3 * 4;
    unsigned short* xb      = (unsigned short*)ws;                 ws += (size_t)N_TOK * C_DIM * 2;
    unsigned short* fc_img  = (unsigned short*)ws;                 ws += (size_t)E_ALL * C_DIM * H_DIM * 2;
    unsigned short* pj_img  = (unsigned short*)ws;                 ws += (size_t)E_ALL * C_DIM * H_DIM * 2;
    unsigned short* Yp      = (unsigned short*)ws;                 // ~18 MB

    hipMemsetAsync(cnt, 0, 256, stream);
    gate_kernel<<<N_TOK, 64, 0, stream>>>(x, Wg, ebias, rw, cnt, toks, se, sp, sw, xb);
    prep_fc<<<dim3(NSL, E_ALL), 256, 0, stream>>>(Wfc, fc_img);
    prep_pj<<<dim3(NSL, E_ALL), 256, 0, stream>>>(Wpj, pj_img);
    finalize<<<1, 64, 0, stream>>>(cnt, seg, map);
    expert_kernel<<<MAXBLK, 256, 0, stream>>>(
        xb, fc_img, pj_img, cnt, seg, toks, map, Yp);
    combine_kernel<<<(N_TOK * 32) / 256, 256, 0, stream>>>(Yp, seg, se, sp, sw, out);
}

// Round 10
// 197.846 us; speedup vs baseline: 7.2182x; 1.5888x over previous
//
#include <hip/hip_runtime.h>
#include <hip/hip_bf16.h>
#include <cfloat>

#define N_TOK 8192
#define C_DIM 256
#define H_DIM 1024
#define E_ALL 32
#define E_RT  31
#define HS    128                     // h per image slice (prep granularity)
#define NSL   8                       // slices
#define TN    128                     // tokens per block (4 waves x 32)
#define HC2   32                      // h per step
#define NST   (H_DIM / HC2)           // 32 steps
#define STEP_B16 16384                // bytes per weight-matrix step chunk
#define SLICE_B (HS * C_DIM * 2)      // 64 KB per slice
#define MAXBLK 287                    // 64 (e0) + 192 + 31 (routed ceil bound)
#define TG    32                      // tokens per gate block

typedef __attribute__((ext_vector_type(8))) short bf16x8;
typedef __attribute__((ext_vector_type(4))) float f32x4;

__device__ __forceinline__ unsigned short f2bf(float f) {
    return __builtin_bit_cast(unsigned short, __float2bfloat16(f));
}
__device__ __forceinline__ float bf2f(unsigned short u) {
    unsigned int x = ((unsigned int)u) << 16;
    return __builtin_bit_cast(float, x);
}
__device__ __forceinline__ void gld16(void* lds, const void* g) {
    __builtin_amdgcn_global_load_lds(
        (const __attribute__((address_space(1))) void*)g,
        (__attribute__((address_space(3))) void*)lds, 16, 0, 0);
}

// ---------------- gating: 32 tokens/block, LDS Wg, aggregated atomics -------
__global__ __launch_bounds__(128)
void gate_kernel(const float* __restrict__ x, const float* __restrict__ Wg,
                 const float* __restrict__ ebias,
                 float* __restrict__ rw, int* __restrict__ cnt,
                 int* __restrict__ toks,
                 int* __restrict__ se, int* __restrict__ sp, float* __restrict__ sw,
                 unsigned short* __restrict__ xb)
{
    const int n0  = blockIdx.x * TG;
    const int tid = threadIdx.x;
    const int w    = tid >> 6;        // wave 0/1 -> tokens n0+w*16 .. +15
    const int lane = tid & 63;
    const int e    = lane & 31;       // expert (valid < 31)
    const int h    = lane >> 5;       // c-half

    __shared__ float WgL[C_DIM * 32];     // [c][e] padded to 32 -> bank = e
    __shared__ float xsW[2][C_DIM];       // per-wave token row
    __shared__ int   lcnt[E_RT];
    __shared__ int   gbase[E_RT];
    __shared__ int   tokE[TG][3];
    __shared__ int   tokLP[TG][3];
    __shared__ float tokW[TG][3];

    // stage Wg (256x31 f32) -> WgL[c*32+e], coalesced float4 reads
    for (int i = tid; i < C_DIM * E_RT / 4; i += 128) {
        const float4 v = ((const float4*)Wg)[i];
        const int l = i * 4;
        #pragma unroll
        for (int j = 0; j < 4; ++j) {
            const int lj = l + j, c = lj / E_RT, ee = lj - c * E_RT;
            const float vv = (j == 0) ? v.x : (j == 1) ? v.y : (j == 2) ? v.z : v.w;
            WgL[c * 32 + ee] = vv;
        }
    }
    if (tid < E_RT) lcnt[tid] = 0;
    __syncthreads();

    const float eb = (e < E_RT) ? ebias[e] : 0.f;

    #pragma unroll 1
    for (int j = 0; j < 16; ++j) {
        const int n = n0 + w * 16 + j;
        // load token row; fold bf16 conversion (prep_x)
        const float4 xv = ((const float4*)(x + (size_t)n * C_DIM))[lane];
        ((float4*)xsW[w])[lane] = xv;
        {
            ushort4 b;
            b.x = f2bf(xv.x); b.y = f2bf(xv.y); b.z = f2bf(xv.z); b.w = f2bf(xv.w);
            ((ushort4*)(xb + (size_t)n * C_DIM))[lane] = b;
        }
        // dot: lane (e,h) accumulates over its 128-c half
        float p0 = 0.f, p1 = 0.f, p2 = 0.f, p3 = 0.f;
        const int cb = h * 128;
        #pragma unroll
        for (int c4 = 0; c4 < 32; ++c4) {
            const float4 xq = *(const float4*)&xsW[w][cb + c4 * 4];
            p0 = fmaf(xq.x, WgL[(cb + c4 * 4 + 0) * 32 + e], p0);
            p1 = fmaf(xq.y, WgL[(cb + c4 * 4 + 1) * 32 + e], p1);
            p2 = fmaf(xq.z, WgL[(cb + c4 * 4 + 2) * 32 + e], p2);
            p3 = fmaf(xq.w, WgL[(cb + c4 * 4 + 3) * 32 + e], p3);
        }
        float part = (p0 + p1) + (p2 + p3);
        part += __shfl_xor(part, 32);                 // combine halves
        const float logit = (lane < E_RT) ? part : -FLT_MAX;

        // softmax over lanes 0..30
        float m = logit;
        for (int off = 32; off; off >>= 1) m = fmaxf(m, __shfl_xor(m, off));
        const float ev = (lane < E_RT) ? expf(logit - m) : 0.f;
        float sum = ev;
        for (int off = 32; off; off >>= 1) sum += __shfl_xor(sum, off);
        const float gate = ev / sum;
        const float biased = (lane < E_RT) ? gate + eb : -FLT_MAX;

        // top-3, lowest-index tie-break
        float val[3]; int idx[3];
        float cur = biased;
        #pragma unroll
        for (int k = 0; k < 3; ++k) {
            float mk = cur;
            for (int off = 32; off; off >>= 1) mk = fmaxf(mk, __shfl_xor(mk, off));
            unsigned long long ball = __ballot(cur == mk && lane < E_RT);
            int sel = __ffsll(ball) - 1;
            val[k] = mk; idx[k] = sel;
            if (lane == sel) cur = -FLT_MAX;
        }

        const float st = val[0] + val[1] + val[2];
        const float wr0 = val[0] / st * 0.75f;
        const float wr1 = val[1] / st * 0.75f;
        const float wr2 = val[2] / st * 0.75f;

        if (lane < E_ALL) {
            float v = 0.f;
            if (lane == 0)          v = 0.25f;
            if (lane == idx[0] + 1) v = wr0;
            if (lane == idx[1] + 1) v = wr1;
            if (lane == idx[2] + 1) v = wr2;
            rw[(size_t)n * E_ALL + lane] = v;
        }

        if (lane == 0) {
            const float wv[3] = {wr0, wr1, wr2};
            const int tl = w * 16 + j;
            #pragma unroll
            for (int k = 0; k < 3; ++k) {
                const int lp = atomicAdd(&lcnt[idx[k]], 1);   // LDS atomic
                tokE[tl][k] = idx[k];
                tokLP[tl][k] = lp;
                tokW[tl][k] = wv[k];
            }
        }
    }

    __syncthreads();
    if (tid < E_RT) gbase[tid] = atomicAdd(&cnt[tid], lcnt[tid]);  // 1/blk/e
    __syncthreads();

    if (tid < TG) {
        const int n = n0 + tid;
        #pragma unroll
        for (int k = 0; k < 3; ++k) {
            const int e31 = tokE[tid][k];
            const int pos = gbase[e31] + tokLP[tid][k];
            toks[e31 * N_TOK + pos] = n;
            se[n * 3 + k] = e31;
            sp[n * 3 + k] = pos;
            sw[n * 3 + k] = tokW[tid][k];
        }
    }
}

// seg + dense active-block map (contiguous dispatch -> even CU spread)
__global__ void finalize(const int* __restrict__ cnt, int* __restrict__ seg,
                         unsigned int* __restrict__ map) {
    if (threadIdx.x == 0) {
        int blk = 0;
        for (int t = 0; t < N_TOK / TN; ++t) map[blk++] = (unsigned)t;   // e = 0
        int b = N_TOK;
        seg[0] = 0;
        for (int i = 0; i < E_RT; ++i) {
            seg[i + 1] = b; b += (cnt[i] + 63) & ~63;
            const int nt = (cnt[i] + TN - 1) / TN;
            for (int t = 0; t < nt; ++t)
                map[blk++] = ((unsigned)(i + 1) << 8) | (unsigned)t;
        }
        for (; blk < MAXBLK; ++blk) map[blk] = 0xFFFFFFFFu;
    }
}

// -------------------------------------- weight prep: MFMA-fragment images ---
__global__ __launch_bounds__(256)
void prep_fc(const float* __restrict__ Wfc, unsigned short* __restrict__ img)
{
    const int s = blockIdx.x, e = blockIdx.y;
    const int h0 = s * HS;
    __shared__ unsigned short tb[C_DIM * HS];     // [c][hh] bf16, 64 KB
    const int tid = threadIdx.x;
    #pragma unroll
    for (int i = 0; i < 32; ++i) {
        const int fidx = i * 1024 + tid * 4;
        const int c = fidx >> 7, hh = fidx & 127;
        const float4 v = *(const float4*)(Wfc + ((size_t)e * C_DIM + c) * H_DIM + h0 + hh);
        ushort4 b;
        b.x = f2bf(v.x); b.y = f2bf(v.y); b.z = f2bf(v.z); b.w = f2bf(v.w);
        *(ushort4*)(tb + c * HS + hh) = b;
    }
    __syncthreads();
    const int lane = tid & 63, w = tid >> 6;
    const int l15 = lane & 15, kg = lane >> 4;
    unsigned short* dst = img + ((size_t)e * NSL + s) * (SLICE_B / 2);
    for (int li = w; li < 64; li += 4) {
        const int ct = li >> 3, ks = li & 7;      // ct-major
        bf16x8 v;
        #pragma unroll
        for (int j = 0; j < 8; ++j)
            v[j] = (short)tb[(ks * 32 + kg * 8 + j) * HS + ct * 16 + l15];
        *(bf16x8*)(dst + (size_t)li * 512 + lane * 8) = v;
    }
}

__global__ __launch_bounds__(256)
void prep_pj(const float* __restrict__ Wpj, unsigned short* __restrict__ img)
{
    const int s = blockIdx.x, e = blockIdx.y;
    const int h0 = s * HS;
    __shared__ unsigned short tb[HS * C_DIM];     // [r(h)][cc] bf16, 64 KB
    const int tid = threadIdx.x;
    #pragma unroll
    for (int i = 0; i < 32; ++i) {
        const int fidx = i * 1024 + tid * 4;
        const int r = fidx >> 8, cc = fidx & 255;
        const float4 v = *(const float4*)(Wpj + ((size_t)e * H_DIM + h0 + r) * C_DIM + cc);
        ushort4 b;
        b.x = f2bf(v.x); b.y = f2bf(v.y); b.z = f2bf(v.z); b.w = f2bf(v.w);
        *(ushort4*)(tb + r * C_DIM + cc) = b;
    }
    __syncthreads();
    const int lane = tid & 63, w = tid >> 6;
    const int l15 = lane & 15, kg = lane >> 4;
    unsigned short* dst = img + ((size_t)e * NSL + s) * (SLICE_B / 2);
    for (int li = w; li < 64; li += 4) {
        const int ks = li >> 4, ct = li & 15;
        bf16x8 v;
        #pragma unroll
        for (int j = 0; j < 8; ++j)
            v[j] = (short)tb[(ks * 32 + kg * 8 + j) * C_DIM + ct + l15 * 16];
        *(bf16x8*)(dst + (size_t)li * 512 + lane * 8) = v;
    }
}

// ----------------------------- experts: dense map, 4 waves, 32 tokens/wave --
__global__ __launch_bounds__(256)
void expert_kernel(const unsigned short* __restrict__ xb,
                   const unsigned short* __restrict__ fc_img,
                   const unsigned short* __restrict__ pj_img,
                   const int* __restrict__ cnt,
                   const int* __restrict__ seg,
                   const int* __restrict__ toks,
                   const unsigned int* __restrict__ map,
                   unsigned short* __restrict__ Yp)
{
    const unsigned int mp = map[blockIdx.x];
    if (mp == 0xFFFFFFFFu) return;
    const int e = mp >> 8;
    const int tstart = (int)(mp & 255u) * TN;
    const int count = (e == 0) ? N_TOK : cnt[e - 1];
    const int tend = min(tstart + TN, count);
    const int segbase = seg[e];

    __shared__ unsigned short fc0[STEP_B16 / 2];
    __shared__ unsigned short fc1[STEP_B16 / 2];
    __shared__ unsigned short pj0[STEP_B16 / 2];
    __shared__ unsigned short pj1[STEP_B16 / 2];
    __shared__ unsigned short Hs[TN * HC2];       // 8 KB, wave-local rows

    const int tid  = threadIdx.x;
    const int lane = tid & 63;
    const int w    = tid >> 6;                    // 0..3, owns rows w*32..+31
    const int l15  = lane & 15;
    const int kg   = lane >> 4;

    // two token rows per thread-slot (mg = 0,1)
    int tok0 = 0, tok1 = 0;
    {
        const int p0 = tstart + w * 32 + l15;
        const int p1 = p0 + 16;
        if (p0 < tend) tok0 = (e == 0) ? p0 : toks[(e - 1) * N_TOK + p0];
        if (p1 < tend) tok1 = (e == 0) ? p1 : toks[(e - 1) * N_TOK + p1];
    }

    bf16x8 aF0[8], aF1[8];
    {
        const unsigned short* xr0 = xb + (size_t)tok0 * C_DIM + kg * 8;
        const unsigned short* xr1 = xb + (size_t)tok1 * C_DIM + kg * 8;
        #pragma unroll
        for (int ks = 0; ks < 8; ++ks) {
            aF0[ks] = *(const bf16x8*)(xr0 + ks * 32);
            aF1[ks] = *(const bf16x8*)(xr1 + ks * 32);
        }
    }

    f32x4 accP0[16], accP1[16];
    #pragma unroll
    for (int i = 0; i < 16; ++i) {
        accP0[i] = (f32x4){0.f, 0.f, 0.f, 0.f};
        accP1[i] = (f32x4){0.f, 0.f, 0.f, 0.f};
    }

    const char* fsrc = (const char*)fc_img + (size_t)e * NSL * SLICE_B;
    const char* psrc = (const char*)pj_img + (size_t)e * NSL * SLICE_B;

    auto STAGE16 = [&](unsigned short* dst, const char* src) {  // 16 KB linear
        #pragma unroll
        for (int i = 0; i < 4; ++i) {             // 256 thr x 16B x 4
            const int off = i * 4096 + tid * 16;
            gld16((char*)dst + off, src + off);
        }
    };

    auto COMPUTE = [&](const unsigned short* bF, const unsigned short* bP) {
        // ---- fc: 32 tok x 32 h, K=256; each B-frag read feeds 2 MFMAs
        f32x4 accFa[2], accFb[2];
        accFa[0] = (f32x4){0.f, 0.f, 0.f, 0.f};
        accFa[1] = (f32x4){0.f, 0.f, 0.f, 0.f};
        accFb[0] = (f32x4){0.f, 0.f, 0.f, 0.f};
        accFb[1] = (f32x4){0.f, 0.f, 0.f, 0.f};
        #pragma unroll
        for (int ks = 0; ks < 8; ++ks) {
            #pragma unroll
            for (int ct = 0; ct < 2; ++ct) {
                const bf16x8 b = *(const bf16x8*)((const char*)bF +
                                   (((ct * 8 + ks) * 64 + lane) << 4));
                accFa[ct] = __builtin_amdgcn_mfma_f32_16x16x32_bf16(aF0[ks], b, accFa[ct], 0, 0, 0);
                accFb[ct] = __builtin_amdgcn_mfma_f32_16x16x32_bf16(aF1[ks], b, accFb[ct], 0, 0, 0);
            }
        }
        // ---- relu^2 -> Hs (wave-local rows)
        #pragma unroll
        for (int ct = 0; ct < 2; ++ct) {
            #pragma unroll
            for (int r = 0; r < 4; ++r) {
                {
                    const int hr = w * 32 + kg * 4 + r;
                    float v = fmaxf(accFa[ct][r], 0.f); v *= v;
                    const int byte = (hr * 64 + (ct * 16 + l15) * 2) ^ ((hr & 7) << 4);
                    *(unsigned short*)((char*)Hs + byte) = f2bf(v);
                }
                {
                    const int hr = w * 32 + 16 + kg * 4 + r;
                    float v = fmaxf(accFb[ct][r], 0.f); v *= v;
                    const int byte = (hr * 64 + (ct * 16 + l15) * 2) ^ ((hr & 7) << 4);
                    *(unsigned short*)((char*)Hs + byte) = f2bf(v);
                }
            }
        }
        // ---- proj: 32 tok x 256 cc, K=32; lane owns cc = l15*16 + ct
        const int ar0 = w * 32 + l15;
        const int ar1 = ar0 + 16;
        const int ab0 = (ar0 * 64 + kg * 16) ^ ((ar0 & 7) << 4);
        const int ab1 = (ar1 * 64 + kg * 16) ^ ((ar1 & 7) << 4);
        const bf16x8 av0 = *(const bf16x8*)((const char*)Hs + ab0);
        const bf16x8 av1 = *(const bf16x8*)((const char*)Hs + ab1);
        #pragma unroll
        for (int ct = 0; ct < 16; ++ct) {
            const bf16x8 b = *(const bf16x8*)((const char*)bP +
                               ((ct * 64 + lane) << 4));
            accP0[ct] = __builtin_amdgcn_mfma_f32_16x16x32_bf16(av0, b, accP0[ct], 0, 0, 0);
            accP1[ct] = __builtin_amdgcn_mfma_f32_16x16x32_bf16(av1, b, accP1[ct], 0, 0, 0);
        }
    };

    STAGE16(fc0, fsrc);
    STAGE16(pj0, psrc);
    asm volatile("" ::: "memory");

    #pragma unroll 1
    for (int t = 0; t < NST - 1; ++t) {
        if (t & 1) { STAGE16(fc0, fsrc + (size_t)(t + 1) * STEP_B16);
                     STAGE16(pj0, psrc + (size_t)(t + 1) * STEP_B16); }
        else       { STAGE16(fc1, fsrc + (size_t)(t + 1) * STEP_B16);
                     STAGE16(pj1, psrc + (size_t)(t + 1) * STEP_B16); }
        asm volatile("s_waitcnt vmcnt(8)" ::: "memory");   // cur step landed
        __builtin_amdgcn_s_barrier();
        if (t & 1) COMPUTE(fc1, pj1);
        else       COMPUTE(fc0, pj0);
        __builtin_amdgcn_s_barrier();                       // WAR before overwrite
    }
    asm volatile("s_waitcnt vmcnt(0)" ::: "memory");
    __builtin_amdgcn_s_barrier();
    COMPUTE(fc1, pj1);                                      // NST-1 odd -> buf1

    // ---- plain coalesced stores: lane owns 16 consecutive cc (32 B)
    #pragma unroll
    for (int r = 0; r < 4; ++r) {
        const int m0 = tstart + w * 32 + kg * 4 + r;
        if (m0 < tend) {
            unsigned short* d2 = Yp + (size_t)(segbase + m0) * C_DIM + l15 * 16;
            bf16x8 u0, u1;
            #pragma unroll
            for (int j = 0; j < 8; ++j) {
                u0[j] = (short)f2bf(accP0[j][r]);
                u1[j] = (short)f2bf(accP0[j + 8][r]);
            }
            *(bf16x8*)d2       = u0;
            *(bf16x8*)(d2 + 8) = u1;
        }
        const int m1 = tstart + w * 32 + 16 + kg * 4 + r;
        if (m1 < tend) {
            unsigned short* d2 = Yp + (size_t)(segbase + m1) * C_DIM + l15 * 16;
            bf16x8 u0, u1;
            #pragma unroll
            for (int j = 0; j < 8; ++j) {
                u0[j] = (short)f2bf(accP1[j][r]);
                u1[j] = (short)f2bf(accP1[j + 8][r]);
            }
            *(bf16x8*)d2       = u0;
            *(bf16x8*)(d2 + 8) = u1;
        }
    }
}

// --------------------------------------------------------------- combine ----
__global__ __launch_bounds__(256)
void combine_kernel(const unsigned short* __restrict__ Yp,
                    const int* __restrict__ seg,
                    const int* __restrict__ se, const int* __restrict__ sp,
                    const float* __restrict__ sw,
                    float* __restrict__ out)
{
    const int t = blockIdx.x * 256 + threadIdx.x;
    const int n = t >> 5;
    const int c0 = (t & 31) * 8;

    float acc[8];
    {
        const bf16x8 y = *(const bf16x8*)(Yp + (size_t)n * C_DIM + c0);
        #pragma unroll
        for (int i = 0; i < 8; ++i) acc[i] = 0.25f * bf2f((unsigned short)y[i]);
    }
    #pragma unroll
    for (int k = 0; k < 3; ++k) {
        const int e = se[n * 3 + k];
        const int row = seg[e + 1] + sp[n * 3 + k];
        const float wgt = sw[n * 3 + k];
        const bf16x8 y = *(const bf16x8*)(Yp + (size_t)row * C_DIM + c0);
        #pragma unroll
        for (int i = 0; i < 8; ++i) acc[i] = fmaf(wgt, bf2f((unsigned short)y[i]), acc[i]);
    }
    float4 o0 = make_float4(acc[0], acc[1], acc[2], acc[3]);
    float4 o1 = make_float4(acc[4], acc[5], acc[6], acc[7]);
    *(float4*)(out + (size_t)n * C_DIM + c0)     = o0;
    *(float4*)(out + (size_t)n * C_DIM + c0 + 4) = o1;
}

// ---------------------------------------------------------------- launch ----
extern "C" void kernel_launch(void* const* d_in, const int* in_sizes, int n_in,
                              void* d_out, int out_size, void* d_ws, size_t ws_size,
                              hipStream_t stream) {
    const float* x     = (const float*)d_in[0];
    const float* Wg    = (const float*)d_in[1];
    const float* Wfc   = (const float*)d_in[2];
    const float* Wpj   = (const float*)d_in[3];
    const float* ebias = (const float*)d_in[4];

    float* out = (float*)d_out;                       // [N, C]
    float* rw  = out + (size_t)N_TOK * C_DIM;         // [N, 32]

    char* ws = (char*)d_ws;
    int*          cnt  = (int*)ws;                                 ws += 256;
    int*          seg  = (int*)ws;                                 ws += 256;
    unsigned int* map  = (unsigned int*)ws;                        ws += 2048;
    int*   toks = (int*)ws;                                        ws += (size_t)E_RT * N_TOK * 4;
    int*   se   = (int*)ws;                                        ws += (size_t)N_TOK * 3 * 4;
    int*   sp   = (int*)ws;                                        ws += (size_t)N_TOK * 3 * 4;
    float* sw   = (float*)ws;                                      ws += (size_t)N_TOK * 3 * 4;
    unsigned short* xb      = (unsigned short*)ws;                 ws += (size_t)N_TOK * C_DIM * 2;
    unsigned short* fc_img  = (unsigned short*)ws;                 ws += (size_t)E_ALL * C_DIM * H_DIM * 2;
    unsigned short* pj_img  = (unsigned short*)ws;                 ws += (size_t)E_ALL * C_DIM * H_DIM * 2;
    unsigned short* Yp      = (unsigned short*)ws;                 // ~18 MB

    hipMemsetAsync(cnt, 0, 256, stream);
    gate_kernel<<<N_TOK / TG, 128, 0, stream>>>(x, Wg, ebias, rw, cnt, toks, se, sp, sw, xb);
    prep_fc<<<dim3(NSL, E_ALL), 256, 0, stream>>>(Wfc, fc_img);
    prep_pj<<<dim3(NSL, E_ALL), 256, 0, stream>>>(Wpj, pj_img);
    finalize<<<1, 64, 0, stream>>>(cnt, seg, map);
    expert_kernel<<<MAXBLK, 256, 0, stream>>>(
        xb, fc_img, pj_img, cnt, seg, toks, map, Yp);
    combine_kernel<<<(N_TOK * 32) / 256, 256, 0, stream>>>(Yp, seg, se, sp, sw, out);
}